// Round 8
// baseline (1290.543 us; speedup 1.0000x reference)
//
#include <hip/hip_runtime.h>

#define D 256

typedef unsigned short u16;
typedef unsigned int u32;
typedef __attribute__((ext_vector_type(8))) short short8;
typedef __attribute__((ext_vector_type(4))) float f32x4;
typedef __attribute__((ext_vector_type(16))) float f32x16;

// ---------------- bf16 <-> f32, split-pack ----------------
__device__ __forceinline__ float b2f(u16 u) {
    return __uint_as_float(((u32)u) << 16);
}
__device__ __forceinline__ u16 f2b(float f) {
    u32 u = __float_as_uint(f);
    return (u16)((u + 0x7FFFu + ((u >> 16) & 1u)) >> 16);  // RNE
}
__device__ __forceinline__ u32 packf(float v) {
    u16 h = f2b(v);
    u16 l = f2b(v - b2f(h));
    return ((u32)h << 16) | l;
}
__device__ __forceinline__ float unpackf(u32 p) {
    return b2f((u16)(p >> 16)) + b2f((u16)(p & 0xffffu));
}
template<typename T> __device__ __forceinline__ float ld1(const T* p);
template<> __device__ __forceinline__ float ld1<u16>(const u16* p) { return b2f(*p); }
template<> __device__ __forceinline__ float ld1<u32>(const u32* p) { return unpackf(*p); }

// ---------------- ordered-uint float atomic max ----------------
__device__ __forceinline__ u32 f2ord(float f) {
    u32 b = __float_as_uint(f);
    return (b & 0x80000000u) ? ~b : (b | 0x80000000u);
}
__device__ __forceinline__ float ord2f(u32 u) {
    return (u & 0x80000000u) ? __uint_as_float(u & 0x7fffffffu)
                             : __uint_as_float(~u);
}

__device__ __forceinline__ float wred(float v) {
#pragma unroll
    for (int m = 32; m; m >>= 1) v += __shfl_xor(v, m);
    return v;
}

// async global(16B/lane) -> LDS (wave-uniform base + lane*16)
__device__ __forceinline__ void gl_lds16(const u16* g, u16* l) {
    __builtin_amdgcn_global_load_lds(
        (__attribute__((address_space(1))) void*)(u16*)g,
        (__attribute__((address_space(3))) void*)l, 16, 0, 0);
}

// ======== gemm2: single-term MFMA GEMM, R2-verified config (locked) ========
// C = act(A[M,K] @ W[N,K]^T + b). A bf16 u16; W hi-plane u16.
// 128x256 tile, single 48KB buffer, 2 barriers/step, 3 blocks/CU. BK=64.
// Conflict-free swizzle key(r) = (r&7) ^ ((r>>3)&3) (measured: conflicts=0).
// R3-R5: dbuf variants all regressed; this is the local optimum.
// M%128==0, N%256==0, K%64==0.
template<int ACT>
__global__ __launch_bounds__(512, 4)
void gemm2(const u16* __restrict__ A, const u16* __restrict__ Whi,
           const float* __restrict__ bias, u16* __restrict__ C,
           int M, int N, int K)
{
    __shared__ u16 sA[128 * 64];       // 16 KB
    __shared__ u16 sWh[256 * 64];      // 32 KB

    const int tid  = threadIdx.x;
    const int lane = tid & 63;
    const int w    = tid >> 6;             // wave 0..7
    const int wm   = (w & 1) * 64;
    const int wn   = (w >> 1) * 64;
    const int row0 = blockIdx.x * 128;
    const int col0 = blockIdx.y * 256;

    f32x16 acc[2][2];
#pragma unroll
    for (int i = 0; i < 2; ++i)
#pragma unroll
        for (int j = 0; j < 2; ++j)
#pragma unroll
            for (int r = 0; r < 16; ++r) acc[i][j][r] = 0.f;

    const int r31   = lane & 31;
    const int khalf = lane >> 5;
    const int skey  = (r31 & 7) ^ ((r31 >> 3) & 3);
    const int l8r = lane >> 3;
    const int l8c = lane & 7;

    for (int k0 = 0; k0 < K; k0 += 64) {
#pragma unroll
        for (int s = 0; s < 4; ++s) {
            const int rbase = w * 32 + s * 8;
            const int row = rbase + l8r;
            const int gch = l8c ^ (row & 7) ^ s;
            const size_t gW = (size_t)(col0 + row) * K + k0 + gch * 8;
            gl_lds16(Whi + gW, sWh + rbase * 64);
        }
#pragma unroll
        for (int s = 0; s < 2; ++s) {
            const int rbase = w * 16 + s * 8;
            const int row = rbase + l8r;
            const int gch = l8c ^ (row & 7) ^ ((w * 2 + s) & 3);
            const size_t gA = (size_t)(row0 + row) * K + k0 + gch * 8;
            gl_lds16(A + gA, sA + rbase * 64);
        }
        __syncthreads();

#pragma unroll
        for (int w4 = 0; w4 < 4; ++w4) {
            const int slot = ((w4 * 2 + khalf) ^ skey) * 8;
            short8 af[2], wf[2];
#pragma unroll
            for (int i = 0; i < 2; ++i)
                af[i] = *(const short8*)(sA + (wm + i * 32 + r31) * 64 + slot);
#pragma unroll
            for (int j = 0; j < 2; ++j)
                wf[j] = *(const short8*)(sWh + (wn + j * 32 + r31) * 64 + slot);
#pragma unroll
            for (int i = 0; i < 2; ++i)
#pragma unroll
                for (int j = 0; j < 2; ++j)
                    acc[i][j] = __builtin_amdgcn_mfma_f32_32x32x16_bf16(af[i], wf[j], acc[i][j], 0, 0, 0);
        }
        __syncthreads();
    }

#pragma unroll
    for (int j = 0; j < 2; ++j) {
        const int col = col0 + wn + j * 32 + r31;
        const float bb = bias[col];
#pragma unroll
        for (int i = 0; i < 2; ++i) {
            const int rowb = row0 + wm + i * 32 + 4 * khalf;
#pragma unroll
            for (int reg = 0; reg < 16; ++reg) {
                const int row = rowb + (reg & 3) + 8 * (reg >> 2);
                float v = acc[i][j][reg] + bb;
                if (ACT) v = v > 0.f ? v : 0.2f * v;
                C[(size_t)row * N + col] = f2b(v);
            }
        }
    }
}

// ======== gemm2f: W5 GEMM with FUSED final_k epilogue ========
// h = A[M,768] @ W5[256,768]^T + b5 (f32, never rounded);
// a = h + q (q = Qn row, bf16); t = LN(a)*gfin+bfin;
// out[e0+row] = dot(t, wvec) + bvec.  N=256 fixed -> block owns complete
// rows (grid (M/128,1)) so row-LN is block-local: r31-butterfly shfl +
// 4-column-group LDS reduce (reuses sA after the last K-loop barrier).
// Removes the final_k kernel + the c5 (h) round-trip entirely.
// M%128==0, K%64==0.
__global__ __launch_bounds__(512, 4)
void gemm2f(const u16* __restrict__ A, const u16* __restrict__ Whi,
            const float* __restrict__ bias, const u16* __restrict__ Qn,
            const float* __restrict__ gfin, const float* __restrict__ bfin,
            const float* __restrict__ wvec, const float* __restrict__ bvec,
            float* __restrict__ out, int e0, int M, int K)
{
    constexpr int N = 256;
    __shared__ u16 sA[128 * 64];       // 16 KB (reused as f32 red after loop)
    __shared__ u16 sWh[256 * 64];      // 32 KB

    const int tid  = threadIdx.x;
    const int lane = tid & 63;
    const int w    = tid >> 6;             // wave 0..7
    const int wm   = (w & 1) * 64;
    const int wn   = (w >> 1) * 64;
    const int row0 = blockIdx.x * 128;

    f32x16 acc[2][2];
#pragma unroll
    for (int i = 0; i < 2; ++i)
#pragma unroll
        for (int j = 0; j < 2; ++j)
#pragma unroll
            for (int r = 0; r < 16; ++r) acc[i][j][r] = 0.f;

    const int r31   = lane & 31;
    const int khalf = lane >> 5;
    const int skey  = (r31 & 7) ^ ((r31 >> 3) & 3);
    const int l8r = lane >> 3;
    const int l8c = lane & 7;

    for (int k0 = 0; k0 < K; k0 += 64) {
#pragma unroll
        for (int s = 0; s < 4; ++s) {
            const int rbase = w * 32 + s * 8;
            const int row = rbase + l8r;
            const int gch = l8c ^ (row & 7) ^ s;
            const size_t gW = (size_t)row * K + k0 + gch * 8;
            gl_lds16(Whi + gW, sWh + rbase * 64);
        }
#pragma unroll
        for (int s = 0; s < 2; ++s) {
            const int rbase = w * 16 + s * 8;
            const int row = rbase + l8r;
            const int gch = l8c ^ (row & 7) ^ ((w * 2 + s) & 3);
            const size_t gA = (size_t)(row0 + row) * K + k0 + gch * 8;
            gl_lds16(A + gA, sA + rbase * 64);
        }
        __syncthreads();

#pragma unroll
        for (int w4 = 0; w4 < 4; ++w4) {
            const int slot = ((w4 * 2 + khalf) ^ skey) * 8;
            short8 af[2], wf[2];
#pragma unroll
            for (int i = 0; i < 2; ++i)
                af[i] = *(const short8*)(sA + (wm + i * 32 + r31) * 64 + slot);
#pragma unroll
            for (int j = 0; j < 2; ++j)
                wf[j] = *(const short8*)(sWh + (wn + j * 32 + r31) * 64 + slot);
#pragma unroll
            for (int i = 0; i < 2; ++i)
#pragma unroll
                for (int j = 0; j < 2; ++j)
                    acc[i][j] = __builtin_amdgcn_mfma_f32_32x32x16_bf16(af[i], wf[j], acc[i][j], 0, 0, 0);
        }
        __syncthreads();
    }

    // ---- fused epilogue: a = h + q; row-LN; dot(t, wvec) ----
    // red layout (floats, in sA): [0..511]=s1[row][cg], [512..1023]=s2,
    // [1024..1535]=p. cg = w>>1 (column-group). 6 KB of 16 KB.
    float* red = (float*)sA;
    const int cg = w >> 1;

#pragma unroll
    for (int i = 0; i < 2; ++i) {
#pragma unroll
        for (int reg = 0; reg < 16; ++reg) {
            const int lr = wm + i * 32 + 4 * khalf + (reg & 3) + 8 * (reg >> 2);
            const size_t grow = (size_t)(row0 + lr);
            float s1 = 0.f, s2 = 0.f;
#pragma unroll
            for (int j = 0; j < 2; ++j) {
                const int col = wn + j * 32 + r31;
                float a = acc[i][j][reg] + bias[col] + b2f(Qn[grow * N + col]);
                acc[i][j][reg] = a;                    // keep for pass 2
                s1 += a; s2 += a * a;
            }
#pragma unroll
            for (int m2 = 16; m2; m2 >>= 1) {
                s1 += __shfl_xor(s1, m2);
                s2 += __shfl_xor(s2, m2);
            }
            if (r31 == 0) {
                red[lr * 4 + cg] = s1;
                red[512 + lr * 4 + cg] = s2;
            }
        }
    }
    __syncthreads();

#pragma unroll
    for (int i = 0; i < 2; ++i) {
#pragma unroll
        for (int reg = 0; reg < 16; ++reg) {
            const int lr = wm + i * 32 + 4 * khalf + (reg & 3) + 8 * (reg >> 2);
            float m = (red[lr * 4 + 0] + red[lr * 4 + 1] +
                       red[lr * 4 + 2] + red[lr * 4 + 3]) * (1.f / 256.f);
            float e2 = (red[512 + lr * 4 + 0] + red[512 + lr * 4 + 1] +
                        red[512 + lr * 4 + 2] + red[512 + lr * 4 + 3]) * (1.f / 256.f);
            float rstd = rsqrtf(e2 - m * m + 1e-5f);
            float p = 0.f;
#pragma unroll
            for (int j = 0; j < 2; ++j) {
                const int col = wn + j * 32 + r31;
                float t = (acc[i][j][reg] - m) * rstd * gfin[col] + bfin[col];
                p += t * wvec[col];
            }
#pragma unroll
            for (int m2 = 16; m2; m2 >>= 1) p += __shfl_xor(p, m2);
            if (r31 == 0) red[1024 + lr * 4 + cg] = p;
        }
    }
    __syncthreads();

    if (tid < 128) {
        float v = red[1024 + tid * 4 + 0] + red[1024 + tid * 4 + 1] +
                  red[1024 + tid * 4 + 2] + red[1024 + tid * 4 + 3] + bvec[0];
        out[e0 + row0 + tid] = v;
    }
}

// ======== gemm3w: 3-term split MFMA GEMM, plane-split A, N=256 sweep ========
// C = A @ W^T + b with A = Ah + Al, W = Wh + Wl (3-term: hh + hl + lh).
// 16x16x32, BK=32, 128x256 block tile -> each block owns COMPLETE rows.
// LNF=0: epilogue writes hi-only bf16 (bias only).
// LNF=1: fused lrelu + row-LayerNorm epilogue.
// M%128==0, K%32==0.
template<int LNF>
__global__ __launch_bounds__(512, 4)
void gemm3w(const u16* __restrict__ Ah, const u16* __restrict__ Al,
            const u16* __restrict__ Wh_, const u16* __restrict__ Wl_,
            const float* __restrict__ bias,
            const float* __restrict__ lng, const float* __restrict__ lnb,
            u16* __restrict__ Ch, int M, int K)
{
    constexpr int N = 256;
    __shared__ u16 sAhi[128 * 32];
    __shared__ u16 sAlo[128 * 32];
    __shared__ u16 sWhi[256 * 32];
    __shared__ u16 sWlo[256 * 32];

    const int tid  = threadIdx.x;
    const int lane = tid & 63;
    const int w    = tid >> 6;
    const int wm   = (w & 1) * 64;
    const int wn   = (w >> 1) * 64;
    const int row0 = blockIdx.x * 128;

    f32x4 acc[4][4];
#pragma unroll
    for (int i = 0; i < 4; ++i)
#pragma unroll
        for (int j = 0; j < 4; ++j) acc[i][j] = (f32x4){0.f, 0.f, 0.f, 0.f};

    const int lrow = lane >> 2;
    const int gck  = (lane & 3) ^ ((lane >> 3) & 3);
    const int r15 = lane & 15;
    const int hi16 = lane >> 4;
    const int rck = (hi16 ^ ((r15 >> 1) & 3)) * 8;

    for (int k0 = 0; k0 < K; k0 += 32) {
#pragma unroll
        for (int s = 0; s < 2; ++s) {                  // W: 256 rows
            const int rbase = w * 32 + s * 16;
            const size_t gW = (size_t)(rbase + lrow) * K + k0 + gck * 8;
            gl_lds16(Wh_ + gW, sWhi + rbase * 32);
            gl_lds16(Wl_ + gW, sWlo + rbase * 32);
        }
        {                                              // A: 128 rows
            const int rbase = w * 16;
            const size_t gA = (size_t)(row0 + rbase + lrow) * K + k0 + gck * 8;
            gl_lds16(Ah + gA, sAhi + rbase * 32);
            gl_lds16(Al + gA, sAlo + rbase * 32);
        }
        __syncthreads();

        short8 ah[4], al[4], wh[4], wl[4];
#pragma unroll
        for (int i = 0; i < 4; ++i) {
            const int offA = (wm + i * 16 + r15) * 32 + rck;
            ah[i] = *(const short8*)(sAhi + offA);
            al[i] = *(const short8*)(sAlo + offA);
        }
#pragma unroll
        for (int j = 0; j < 4; ++j) {
            const int offW = (wn + j * 16 + r15) * 32 + rck;
            wh[j] = *(const short8*)(sWhi + offW);
            wl[j] = *(const short8*)(sWlo + offW);
        }
#pragma unroll
        for (int i = 0; i < 4; ++i)
#pragma unroll
            for (int j = 0; j < 4; ++j) {
                acc[i][j] = __builtin_amdgcn_mfma_f32_16x16x32_bf16(ah[i], wh[j], acc[i][j], 0, 0, 0);
                acc[i][j] = __builtin_amdgcn_mfma_f32_16x16x32_bf16(ah[i], wl[j], acc[i][j], 0, 0, 0);
                acc[i][j] = __builtin_amdgcn_mfma_f32_16x16x32_bf16(al[i], wh[j], acc[i][j], 0, 0, 0);
            }
        __syncthreads();
    }

    if (LNF == 0) {
#pragma unroll
        for (int j = 0; j < 4; ++j) {
            const int col = wn + j * 16 + r15;
            const float bb = bias[col];
#pragma unroll
            for (int i = 0; i < 4; ++i) {
                const int rowb = row0 + wm + i * 16 + hi16 * 4;
#pragma unroll
                for (int r = 0; r < 4; ++r)
                    Ch[(size_t)(rowb + r) * N + col] = f2b(acc[i][j][r] + bb);
            }
        }
    } else {
        // fused lrelu + row-LN. red[stat][lrow][cg], stat in {0,1}.
        float* red = (float*)sWhi;                 // 4 KB of the 16 KB buffer
        const int cg = w >> 1;
#pragma unroll
        for (int i = 0; i < 4; ++i) {
            float s1[4] = {0.f, 0.f, 0.f, 0.f};
            float s2[4] = {0.f, 0.f, 0.f, 0.f};
#pragma unroll
            for (int j = 0; j < 4; ++j) {
                const float bb = bias[wn + j * 16 + r15];
#pragma unroll
                for (int r = 0; r < 4; ++r) {
                    float v = acc[i][j][r] + bb;
                    float a = v > 0.f ? v : 0.2f * v;
                    s1[r] += a; s2[r] += a * a;
                }
            }
#pragma unroll
            for (int r = 0; r < 4; ++r) {
#pragma unroll
                for (int m = 8; m; m >>= 1) {
                    s1[r] += __shfl_xor(s1[r], m);
                    s2[r] += __shfl_xor(s2[r], m);
                }
            }
            if (r15 == 0) {
#pragma unroll
                for (int r = 0; r < 4; ++r) {
                    const int lr = wm + i * 16 + hi16 * 4 + r;
                    red[lr * 4 + cg] = s1[r];
                    red[(128 + lr) * 4 + cg] = s2[r];
                }
            }
        }
        __syncthreads();
#pragma unroll
        for (int i = 0; i < 4; ++i) {
#pragma unroll
            for (int r = 0; r < 4; ++r) {
                const int lr = wm + i * 16 + hi16 * 4 + r;
                float m = (red[lr * 4 + 0] + red[lr * 4 + 1] +
                           red[lr * 4 + 2] + red[lr * 4 + 3]) * (1.f / 256.f);
                float e2 = (red[(128 + lr) * 4 + 0] + red[(128 + lr) * 4 + 1] +
                            red[(128 + lr) * 4 + 2] + red[(128 + lr) * 4 + 3]) * (1.f / 256.f);
                float rstd = rsqrtf(e2 - m * m + 1e-5f);
                const size_t grow = (size_t)(row0 + lr);
#pragma unroll
                for (int j = 0; j < 4; ++j) {
                    const int col = wn + j * 16 + r15;
                    float v = acc[i][j][r] + bias[col];
                    float a = v > 0.f ? v : 0.2f * v;
                    Ch[grow * N + col] = f2b((a - m) * rstd * lng[col] + lnb[col]);
                }
            }
        }
    }
}

// ======== gemm3n: node-projection batched GEMM (plane-split A, M-guarded) ===
__global__ __launch_bounds__(512, 4)
void gemm3n(const u16* __restrict__ Ah, const u16* __restrict__ Al,
            const u16* __restrict__ Whi, const u16* __restrict__ Wlo,
            const float* __restrict__ b0, const float* __restrict__ b1,
            const float* __restrict__ b2,
            u32* __restrict__ Cp, int M, int K)
{
    constexpr int N = 256;
    __shared__ u16 sAhi[128 * 32];
    __shared__ u16 sAlo[128 * 32];
    __shared__ u16 sWhi[256 * 32];
    __shared__ u16 sWlo[256 * 32];

    const int tid  = threadIdx.x;
    const int lane = tid & 63;
    const int w    = tid >> 6;
    const int wm   = (w & 1) * 64;
    const int wn   = (w >> 1) * 64;
    const int row0 = blockIdx.x * 128;
    const int y    = blockIdx.y;
    const float* bias = (y == 0) ? b0 : ((y == 1) ? b1 : b2);
    const u16* Wh = Whi + (size_t)y * N * K;
    const u16* Wl = Wlo + (size_t)y * N * K;
    u32* Cy = Cp + (size_t)y * M * N;

    f32x4 acc[4][4];
#pragma unroll
    for (int i = 0; i < 4; ++i)
#pragma unroll
        for (int j = 0; j < 4; ++j) acc[i][j] = (f32x4){0.f, 0.f, 0.f, 0.f};

    const int lrow = lane >> 2;
    const int gck  = (lane & 3) ^ ((lane >> 3) & 3);
    const int r15 = lane & 15;
    const int rck = ((lane >> 4) ^ ((r15 >> 1) & 3)) * 8;

    for (int k0 = 0; k0 < K; k0 += 32) {
#pragma unroll
        for (int s = 0; s < 2; ++s) {
            const int rbase = w * 32 + s * 16;
            const size_t gW = (size_t)(rbase + lrow) * K + k0 + gck * 8;
            gl_lds16(Wh + gW, sWhi + rbase * 32);
            gl_lds16(Wl + gW, sWlo + rbase * 32);
        }
        {
            const int rbase = w * 16;
            int arow = row0 + rbase + lrow;
            if (arow >= M) arow = M - 1;               // per-lane source clamp
            const size_t gA = (size_t)arow * K + k0 + gck * 8;
            gl_lds16(Ah + gA, sAhi + rbase * 32);
            gl_lds16(Al + gA, sAlo + rbase * 32);
        }
        __syncthreads();

        short8 ah[4], al[4], wh[4], wl[4];
#pragma unroll
        for (int i = 0; i < 4; ++i) {
            const int offA = (wm + i * 16 + r15) * 32 + rck;
            ah[i] = *(const short8*)(sAhi + offA);
            al[i] = *(const short8*)(sAlo + offA);
        }
#pragma unroll
        for (int j = 0; j < 4; ++j) {
            const int offW = (wn + j * 16 + r15) * 32 + rck;
            wh[j] = *(const short8*)(sWhi + offW);
            wl[j] = *(const short8*)(sWlo + offW);
        }
#pragma unroll
        for (int i = 0; i < 4; ++i)
#pragma unroll
            for (int j = 0; j < 4; ++j) {
                acc[i][j] = __builtin_amdgcn_mfma_f32_16x16x32_bf16(ah[i], wh[j], acc[i][j], 0, 0, 0);
                acc[i][j] = __builtin_amdgcn_mfma_f32_16x16x32_bf16(ah[i], wl[j], acc[i][j], 0, 0, 0);
                acc[i][j] = __builtin_amdgcn_mfma_f32_16x16x32_bf16(al[i], wh[j], acc[i][j], 0, 0, 0);
            }
        __syncthreads();
    }

#pragma unroll
    for (int j = 0; j < 4; ++j) {
        const int col = wn + j * 16 + r15;
        const float bb = bias[col];
#pragma unroll
        for (int i = 0; i < 4; ++i) {
            const int rowb = row0 + wm + i * 16 + (lane >> 4) * 4;
#pragma unroll
            for (int r = 0; r < 4; ++r) {
                const int row = rowb + r;
                if (row < M)
                    Cy[(size_t)row * N + col] = packf(acc[i][j][r] + bb);
            }
        }
    }
}

// ---------------- x fp32 -> hi/lo bf16 planes ----------------
__global__ void pack_x(const float* __restrict__ x, u16* __restrict__ xh,
                       u16* __restrict__ xl, int n)
{
    int i = blockIdx.x * 256 + threadIdx.x;
    if (i < n) {
        float v = x[i];
        u16 h = f2b(v);
        xh[i] = h;
        xl[i] = f2b(v - b2f(h));
    }
}

// ---------------- weight conversions in ONE launch (21 regions of DD) -------
struct WcvA { const float* s[21]; u16* h[21]; u16* l[21]; };
__global__ __launch_bounds__(256)
void wconv_all(WcvA a, int n)
{
    int i = blockIdx.x * 256 + threadIdx.x;
    if (i >= n) return;
    int r = i >> 16;
    int o = i & 65535;
    float v = a.s[r][o];
    u16 hh = f2b(v);
    a.h[r][o] = hh;
    if (a.l[r]) a.l[r][o] = f2b(v - b2f(hh));
}

// ---------------- Wc = Wq1 @ Wff0 (fp32), bc = bq1 + Wq1 @ bff --------------
__global__ __launch_bounds__(256)
void wcomb(const float* __restrict__ Wq1, const float* __restrict__ Wff0,
           const float* __restrict__ bff, const float* __restrict__ bq1,
           u16* __restrict__ wch, u16* __restrict__ wcl, float* __restrict__ bc)
{
    const int o = blockIdx.x;
    const int j = threadIdx.x;
    const float* wq = Wq1 + (size_t)o * 256;
    float s = 0.f;
    for (int k = 0; k < 256; ++k)
        s = fmaf(wq[k], Wff0[(size_t)k * 256 + j], s);
    u16 h = f2b(s);
    wch[(size_t)o * 256 + j] = h;
    wcl[(size_t)o * 256 + j] = f2b(s - b2f(h));
    float p = wq[j] * bff[j];
    p = wred(p);
    __shared__ float ps[4];
    if ((j & 63) == 0) ps[j >> 6] = p;
    __syncthreads();
    if (j == 0) bc[o] = bq1[o] + ps[0] + ps[1] + ps[2] + ps[3];
}

// ---------------- segment-softmax ----------------
__global__ void seg_init(u32* __restrict__ amax, float* __restrict__ denom, int n)
{
    int i = blockIdx.x * 256 + threadIdx.x;
    if (i < n) { amax[i] = 0u; denom[i] = 0.f; }
}

template<typename TQ, int MODE>
__global__ __launch_bounds__(256)
void attn_alpha(const int* __restrict__ src, const int* __restrict__ dst,
                const TQ* __restrict__ qn, const u32* __restrict__ kn,
                float* __restrict__ alpha, u32* __restrict__ amax, int E)
{
    int e = blockIdx.x * 4 + (threadIdx.x >> 6);
    int lane = threadIdx.x & 63;
    if (e >= E) return;
    int s = src[e], d = dst[e];
    const TQ* qp = MODE ? (qn + (size_t)e * D) : (qn + (size_t)d * D);
    const u32* kp = kn + (size_t)s * D;
    float dot = 0.f;
#pragma unroll
    for (int j = 0; j < 4; ++j)
        dot += ld1(qp + lane * 4 + j) * unpackf(kp[lane * 4 + j]);
    dot = wred(dot);
    if (lane == 0) {
        alpha[e] = dot;
        atomicMax(amax + d, f2ord(dot));
    }
}

__global__ void seg_exp(const int* __restrict__ dst, const float* __restrict__ alpha,
                        const u32* __restrict__ amax, float* __restrict__ ebuf,
                        float* __restrict__ denom, int E)
{
    int e = blockIdx.x * 256 + threadIdx.x;
    if (e >= E) return;
    int d = dst[e];
    float ex = expf(alpha[e] - ord2f(amax[d]));
    ebuf[e] = ex;
    atomicAdd(denom + d, ex);
}

// ---------------- out(local, hi/lo planes) = LN(q + attn*v[src]) ----------------
template<typename TQ, int MODE>
__global__ __launch_bounds__(256)
void attn_out_ln(const int* __restrict__ src, const int* __restrict__ dst,
                 const TQ* __restrict__ qn, const u32* __restrict__ vn,
                 const float* __restrict__ ebuf, const float* __restrict__ denom,
                 const float* __restrict__ g, const float* __restrict__ bb,
                 u16* __restrict__ oh, u16* __restrict__ ol, int e0, int cm)
{
    int le = blockIdx.x * 4 + (threadIdx.x >> 6);
    int lane = threadIdx.x & 63;
    if (le >= cm) return;
    int ge = e0 + le;
    int s = src[ge], d = dst[ge];
    float attn = ebuf[ge] / denom[d];
    const TQ* qp = MODE ? (qn + (size_t)ge * D) : (qn + (size_t)d * D);
    const u32* vp = vn + (size_t)s * D;
    int d0 = lane * 4;
    float a0 = ld1(qp + d0 + 0) + attn * unpackf(vp[d0 + 0]);
    float a1 = ld1(qp + d0 + 1) + attn * unpackf(vp[d0 + 1]);
    float a2 = ld1(qp + d0 + 2) + attn * unpackf(vp[d0 + 2]);
    float a3 = ld1(qp + d0 + 3) + attn * unpackf(vp[d0 + 3]);
    float mean = wred(a0 + a1 + a2 + a3) * (1.f / D);
    float c0 = a0 - mean, c1 = a1 - mean, c2 = a2 - mean, c3 = a3 - mean;
    float var = wred(c0 * c0 + c1 * c1 + c2 * c2 + c3 * c3) * (1.f / D);
    float rstd = rsqrtf(var + 1e-5f);
    float t0 = c0 * rstd * g[d0 + 0] + bb[d0 + 0];
    float t1 = c1 * rstd * g[d0 + 1] + bb[d0 + 1];
    float t2 = c2 * rstd * g[d0 + 2] + bb[d0 + 2];
    float t3 = c3 * rstd * g[d0 + 3] + bb[d0 + 3];
    size_t base = (size_t)le * D + d0;
    ushort4 ph, pl;
    ph.x = f2b(t0); pl.x = f2b(t0 - b2f(ph.x));
    ph.y = f2b(t1); pl.y = f2b(t1 - b2f(ph.y));
    ph.z = f2b(t2); pl.z = f2b(t2 - b2f(ph.z));
    ph.w = f2b(t3); pl.w = f2b(t3 - b2f(ph.w));
    *(ushort4*)(oh + base) = ph;
    *(ushort4*)(ol + base) = pl;
}

extern "C" void kernel_launch(void* const* d_in, const int* in_sizes, int n_in,
                              void* d_out, int out_size, void* d_ws, size_t ws_size,
                              hipStream_t stream)
{
    const int*   ei   = (const int*)d_in[0];
    const float* x    = (const float*)d_in[1];
    const float* Wq   = (const float*)d_in[2];
    const float* bq   = (const float*)d_in[3];
    const float* Wk   = (const float*)d_in[4];
    const float* bk   = (const float*)d_in[5];
    const float* Wv   = (const float*)d_in[6];
    const float* bv   = (const float*)d_in[7];
    const float* Wff  = (const float*)d_in[8];
    const float* bff  = (const float*)d_in[9];
    const float* ga   = (const float*)d_in[10];
    const float* ba   = (const float*)d_in[11];
    const float* gf   = (const float*)d_in[12];
    const float* bf   = (const float*)d_in[13];
    const float* gfin = (const float*)d_in[14];
    const float* bfin = (const float*)d_in[15];
    const float* W3   = (const float*)d_in[16];
    const float* b3   = (const float*)d_in[17];
    const float* W4   = (const float*)d_in[18];
    const float* b4   = (const float*)d_in[19];
    const float* W5   = (const float*)d_in[20];
    const float* b5   = (const float*)d_in[21];
    const float* Wvec = (const float*)d_in[22];
    const float* bvec = (const float*)d_in[23];

    const int E  = in_sizes[0] / 2;     // 160000
    const int Nn = in_sizes[1] / D;
    const int* src = ei;
    const int* dst = ei + E;

    // ---- workspace carve: fixed region ----
    char* base = (char*)d_ws;
    size_t off = 0;
    auto take = [&](size_t bytes) -> void* {
        off = (off + 255) & ~(size_t)255;
        void* r = base + off;
        off += bytes;
        return r;
    };
    u32*   nKV1 = (u32*)take((size_t)2 * Nn * D * 4);    // packed K1,V1
    u16*   q1  = (u16*)take((size_t)E * D * 2);          // hi-only bf16
    float* alpha = (float*)take((size_t)E * 4);
    float* ebuf  = (float*)take((size_t)E * 4);
    u32*   amax  = (u32*)take((size_t)Nn * 4);
    float* denom = (float*)take((size_t)Nn * 4);
    u16* wnh = (u16*)take((size_t)5 * D * D * 2);        // node weights hi (stacked)
    u16* wnl = (u16*)take((size_t)5 * D * D * 2);        // node weights lo
    u16* wff1h = (u16*)take((size_t)D * D * 2); u16* wff1l = (u16*)take((size_t)D * D * 2);
    u16* wch = (u16*)take((size_t)D * D * 2);            // composed Wq1@Wff0 hi
    u16* wcl = (u16*)take((size_t)D * D * 2);            // composed lo
    float* bc = (float*)take((size_t)D * 4);             // composed bias
    u16* w3h = (u16*)take((size_t)3 * D * D * 2);
    u16* w4h = (u16*)take((size_t)9 * D * D * 2);
    u16* w5h = (u16*)take((size_t)3 * D * D * 2);

    // ---- adaptive chunk ----
    const size_t nodeB = (size_t)4 * Nn * D * 4;
    size_t rem = ws_size > off + 8192 ? ws_size - off - 8192 : 0;
    size_t cmA = rem / 4096;
    size_t cmB = rem > nodeB ? (rem - nodeB) / 2048 : 0;
    size_t CMs = (cmA * 2048 >= nodeB) ? cmA : cmB;
    CMs = (CMs / 128) * 128;
    if (CMs > (size_t)E) CMs = E;
    if (CMs > 32768) CMs = 32768;       // one co-residency round for gemm2
    if (CMs < 128) CMs = 128;
    const int CM = (int)CMs;

    // chunk planes: 4 slots of CM*D u16. c1h/c1l = slots 0,1;
    // c4 = slots 0-2 (CM*3D, clobbers c1 after it is dead); slot 3 spare.
    u16* cpl = (u16*)take((size_t)CM * D * 2 * 4);
    u16* c1h = cpl;
    u16* c1l = cpl + (size_t)CM * D;
    u16* c4  = cpl;                                   // CM*3D u16
    size_t zoneB = (size_t)CM * 2048 > nodeB ? (size_t)CM * 2048 : nodeB;
    char* zone = (char*)take(zoneB);
    u16* c2n = (u16*)zone;                            // CM*D u16 (pass 2)
    u16* c3  = (u16*)(zone + (size_t)CM * D * 2);     // CM*3D u16 (pass 2)
    u16* xph = (u16*)zone;                            // Nn*D hi plane (pre)
    u16* xpl = xph + (size_t)Nn * D;                  // Nn*D lo plane
    u32* zQKV = (u32*)(zone + (size_t)Nn * D * 4);    // packed Q0,K0,V0
    u32* zQ0 = zQKV;
    u32* zK0 = zQKV + (size_t)Nn * D;
    u32* zV0 = zQKV + (size_t)2 * Nn * D;
    u32* nK1 = nKV1;
    u32* nV1 = nKV1 + (size_t)Nn * D;

    dim3 blk(256);
    dim3 blk2(512);
    int gridSeg = (Nn + 255) / 256;
    int gridE4  = (E + 3) / 4;
    int gridE   = (E + 255) / 256;
    const int DD = D * D;               // 65536 = 2^16

    // ---- pack x ----
    pack_x<<<(Nn * D + 255) / 256, 256, 0, stream>>>(x, xph, xpl, Nn * D);

    // ---- single-launch weight conversion (21 regions) ----
    WcvA wa;
    const float* ws_[21] = {Wq, Wk, Wv, Wk + DD, Wv + DD, Wff + DD,
                            W3, W3 + DD, W3 + 2 * DD,
                            W4, W4 + DD, W4 + 2 * DD, W4 + 3 * DD, W4 + 4 * DD,
                            W4 + 5 * DD, W4 + 6 * DD, W4 + 7 * DD, W4 + 8 * DD,
                            W5, W5 + DD, W5 + 2 * DD};
    u16* wh_[21] = {wnh, wnh + DD, wnh + 2 * DD, wnh + 3 * DD, wnh + 4 * DD, wff1h,
                    w3h, w3h + DD, w3h + 2 * DD,
                    w4h, w4h + DD, w4h + 2 * DD, w4h + 3 * DD, w4h + 4 * DD,
                    w4h + 5 * DD, w4h + 6 * DD, w4h + 7 * DD, w4h + 8 * DD,
                    w5h, w5h + DD, w5h + 2 * DD};
    u16* wl_[21] = {wnl, wnl + DD, wnl + 2 * DD, wnl + 3 * DD, wnl + 4 * DD, wff1l,
                    nullptr, nullptr, nullptr,
                    nullptr, nullptr, nullptr, nullptr, nullptr,
                    nullptr, nullptr, nullptr, nullptr,
                    nullptr, nullptr, nullptr};
    for (int r = 0; r < 21; ++r) { wa.s[r] = ws_[r]; wa.h[r] = wh_[r]; wa.l[r] = wl_[r]; }
    wconv_all<<<(21 * DD) / 256, 256, 0, stream>>>(wa, 21 * DD);

    // ---- compose pass-1 weights: Wc = Wq1 @ Wff0, bc = bq1 + Wq1 @ bff ----
    wcomb<<<256, 256, 0, stream>>>(Wq + DD, Wff, bff, bq + D, wch, wcl, bc);

    // ---- node projections (batched split-bf16 MFMA) ----
    int gN = (Nn + 127) / 128;
    gemm3n<<<dim3(gN, 3), blk2, 0, stream>>>(xph, xpl, wnh, wnl, bq, bk, bv,
                                             zQKV, Nn, D);
    gemm3n<<<dim3(gN, 2), blk2, 0, stream>>>(xph, xpl, wnh + 3 * DD, wnl + 3 * DD,
                                             bk + D, bv + D, bv,
                                             nKV1, Nn, D);

    // ---- layer-0 segment softmax ----
    seg_init<<<gridSeg, 256, 0, stream>>>(amax, denom, Nn);
    attn_alpha<u32, 0><<<gridE4, blk, 0, stream>>>(src, dst, zQ0, zK0, alpha, amax, E);
    seg_exp<<<gridE, 256, 0, stream>>>(dst, alpha, amax, ebuf, denom, E);

    // ---- pass 1 (chunked): attnLN0 -> (Wq1@Wff0 composed) -> q1 ----
    for (int e0 = 0; e0 < E; e0 += CM) {
        int cm = E - e0 < CM ? E - e0 : CM;
        int gE4 = (cm + 3) / 4;
        dim3 gD3(cm / 128);
        attn_out_ln<u32, 0><<<gE4, blk, 0, stream>>>(src, dst, zQ0, zV0, ebuf, denom,
                                                     ga, ba, c1h, c1l, e0, cm);
        gemm3w<0><<<gD3, blk2, 0, stream>>>(c1h, c1l, wch, wcl, bc,
                                            (const float*)nullptr, (const float*)nullptr,
                                            q1 + (size_t)e0 * D, cm, D);
    }

    // ---- layer-1 segment softmax ----
    seg_init<<<gridSeg, 256, 0, stream>>>(amax, denom, Nn);
    attn_alpha<u16, 1><<<gridE4, blk, 0, stream>>>(src, dst, q1, nK1, alpha, amax, E);
    seg_exp<<<gridE, 256, 0, stream>>>(dst, alpha, amax, ebuf, denom, E);

    // ---- pass 2 (chunked) ----
    for (int e0 = 0; e0 < E; e0 += CM) {
        int cm = E - e0 < CM ? E - e0 : CM;
        int gE4 = (cm + 3) / 4;
        dim3 gD3(cm / 128);
        dim3 g2a(cm / 128, (3 * D) / 256);
        attn_out_ln<u16, 1><<<gE4, blk, 0, stream>>>(src, dst, q1, nV1, ebuf, denom,
                                                     ga + D, ba + D, c1h, c1l, e0, cm);
        // Wff1 GEMM with fused lrelu + LN epilogue -> c2n
        gemm3w<1><<<gD3, blk2, 0, stream>>>(c1h, c1l, wff1h, wff1l, bff + D,
                                            gf, bf, c2n, cm, D);
        gemm2<1><<<g2a, blk2, 0, stream>>>(c2n, w3h, b3, c3, cm, 3 * D, D);
        gemm2<1><<<g2a, blk2, 0, stream>>>(c3, w4h, b4, c4, cm, 3 * D, 3 * D);
        // W5 GEMM with fused final_k epilogue -> logits (no c5 round-trip)
        gemm2f<<<dim3(cm / 128), blk2, 0, stream>>>(c4, w5h, b5, c2n,
                                                    gfin, bfin, Wvec, bvec,
                                                    (float*)d_out, e0, cm, 3 * D);
    }
}

// Round 9
// 1218.843 us; speedup vs baseline: 1.0588x; 1.0588x over previous
//
#include <hip/hip_runtime.h>

#define D 256

typedef unsigned short u16;
typedef unsigned int u32;
typedef __attribute__((ext_vector_type(8))) short short8;
typedef __attribute__((ext_vector_type(4))) float f32x4;
typedef __attribute__((ext_vector_type(16))) float f32x16;

// ---------------- bf16 <-> f32, split-pack ----------------
__device__ __forceinline__ float b2f(u16 u) {
    return __uint_as_float(((u32)u) << 16);
}
__device__ __forceinline__ u16 f2b(float f) {
    u32 u = __float_as_uint(f);
    return (u16)((u + 0x7FFFu + ((u >> 16) & 1u)) >> 16);  // RNE
}
__device__ __forceinline__ u32 packf(float v) {
    u16 h = f2b(v);
    u16 l = f2b(v - b2f(h));
    return ((u32)h << 16) | l;
}
__device__ __forceinline__ float unpackf(u32 p) {
    return b2f((u16)(p >> 16)) + b2f((u16)(p & 0xffffu));
}
template<typename T> __device__ __forceinline__ float ld1(const T* p);
template<> __device__ __forceinline__ float ld1<u16>(const u16* p) { return b2f(*p); }
template<> __device__ __forceinline__ float ld1<u32>(const u32* p) { return unpackf(*p); }

// ---------------- ordered-uint float atomic max ----------------
__device__ __forceinline__ u32 f2ord(float f) {
    u32 b = __float_as_uint(f);
    return (b & 0x80000000u) ? ~b : (b | 0x80000000u);
}
__device__ __forceinline__ float ord2f(u32 u) {
    return (u & 0x80000000u) ? __uint_as_float(u & 0x7fffffffu)
                             : __uint_as_float(~u);
}

__device__ __forceinline__ float wred(float v) {
#pragma unroll
    for (int m = 32; m; m >>= 1) v += __shfl_xor(v, m);
    return v;
}

// async global(16B/lane) -> LDS (wave-uniform base + lane*16)
__device__ __forceinline__ void gl_lds16(const u16* g, u16* l) {
    __builtin_amdgcn_global_load_lds(
        (__attribute__((address_space(1))) void*)(u16*)g,
        (__attribute__((address_space(3))) void*)l, 16, 0, 0);
}

// ======== gemm2: single-term MFMA GEMM, R2-verified config (locked) ========
// C = act(A[M,K] @ W[N,K]^T + b). A bf16 u16; W hi-plane u16.
// 128x256 tile, single 48KB buffer, 2 barriers/step, 3 blocks/CU. BK=64.
// Conflict-free swizzle key(r) = (r&7) ^ ((r>>3)&3) (measured: conflicts=0).
// R3-R5: dbuf variants all regressed; R8: fused final_k epilogue regressed.
// This is the locked local optimum. M%128==0, N%256==0, K%64==0.
template<int ACT>
__global__ __launch_bounds__(512, 4)
void gemm2(const u16* __restrict__ A, const u16* __restrict__ Whi,
           const float* __restrict__ bias, u16* __restrict__ C,
           int M, int N, int K)
{
    __shared__ u16 sA[128 * 64];       // 16 KB
    __shared__ u16 sWh[256 * 64];      // 32 KB

    const int tid  = threadIdx.x;
    const int lane = tid & 63;
    const int w    = tid >> 6;             // wave 0..7
    const int wm   = (w & 1) * 64;
    const int wn   = (w >> 1) * 64;
    const int row0 = blockIdx.x * 128;
    const int col0 = blockIdx.y * 256;

    f32x16 acc[2][2];
#pragma unroll
    for (int i = 0; i < 2; ++i)
#pragma unroll
        for (int j = 0; j < 2; ++j)
#pragma unroll
            for (int r = 0; r < 16; ++r) acc[i][j][r] = 0.f;

    const int r31   = lane & 31;
    const int khalf = lane >> 5;
    const int skey  = (r31 & 7) ^ ((r31 >> 3) & 3);
    const int l8r = lane >> 3;
    const int l8c = lane & 7;

    for (int k0 = 0; k0 < K; k0 += 64) {
#pragma unroll
        for (int s = 0; s < 4; ++s) {
            const int rbase = w * 32 + s * 8;
            const int row = rbase + l8r;
            const int gch = l8c ^ (row & 7) ^ s;
            const size_t gW = (size_t)(col0 + row) * K + k0 + gch * 8;
            gl_lds16(Whi + gW, sWh + rbase * 64);
        }
#pragma unroll
        for (int s = 0; s < 2; ++s) {
            const int rbase = w * 16 + s * 8;
            const int row = rbase + l8r;
            const int gch = l8c ^ (row & 7) ^ ((w * 2 + s) & 3);
            const size_t gA = (size_t)(row0 + row) * K + k0 + gch * 8;
            gl_lds16(A + gA, sA + rbase * 64);
        }
        __syncthreads();

#pragma unroll
        for (int w4 = 0; w4 < 4; ++w4) {
            const int slot = ((w4 * 2 + khalf) ^ skey) * 8;
            short8 af[2], wf[2];
#pragma unroll
            for (int i = 0; i < 2; ++i)
                af[i] = *(const short8*)(sA + (wm + i * 32 + r31) * 64 + slot);
#pragma unroll
            for (int j = 0; j < 2; ++j)
                wf[j] = *(const short8*)(sWh + (wn + j * 32 + r31) * 64 + slot);
#pragma unroll
            for (int i = 0; i < 2; ++i)
#pragma unroll
                for (int j = 0; j < 2; ++j)
                    acc[i][j] = __builtin_amdgcn_mfma_f32_32x32x16_bf16(af[i], wf[j], acc[i][j], 0, 0, 0);
        }
        __syncthreads();
    }

#pragma unroll
    for (int j = 0; j < 2; ++j) {
        const int col = col0 + wn + j * 32 + r31;
        const float bb = bias[col];
#pragma unroll
        for (int i = 0; i < 2; ++i) {
            const int rowb = row0 + wm + i * 32 + 4 * khalf;
#pragma unroll
            for (int reg = 0; reg < 16; ++reg) {
                const int row = rowb + (reg & 3) + 8 * (reg >> 2);
                float v = acc[i][j][reg] + bb;
                if (ACT) v = v > 0.f ? v : 0.2f * v;
                C[(size_t)row * N + col] = f2b(v);
            }
        }
    }
}

// ======== gemm3w: 3-term split MFMA GEMM, plane-split A, N=256 sweep ========
// C = A @ W^T + b with A = Ah + Al, W = Wh + Wl (3-term: hh + hl + lh).
// 16x16x32, BK=32, 128x256 block tile -> each block owns COMPLETE rows.
// LNF=0: epilogue writes hi-only bf16 (bias only).
// LNF=1: fused lrelu + row-LayerNorm epilogue.
// M%128==0, K%32==0.
template<int LNF>
__global__ __launch_bounds__(512, 4)
void gemm3w(const u16* __restrict__ Ah, const u16* __restrict__ Al,
            const u16* __restrict__ Wh_, const u16* __restrict__ Wl_,
            const float* __restrict__ bias,
            const float* __restrict__ lng, const float* __restrict__ lnb,
            u16* __restrict__ Ch, int M, int K)
{
    constexpr int N = 256;
    __shared__ u16 sAhi[128 * 32];
    __shared__ u16 sAlo[128 * 32];
    __shared__ u16 sWhi[256 * 32];
    __shared__ u16 sWlo[256 * 32];

    const int tid  = threadIdx.x;
    const int lane = tid & 63;
    const int w    = tid >> 6;
    const int wm   = (w & 1) * 64;
    const int wn   = (w >> 1) * 64;
    const int row0 = blockIdx.x * 128;

    f32x4 acc[4][4];
#pragma unroll
    for (int i = 0; i < 4; ++i)
#pragma unroll
        for (int j = 0; j < 4; ++j) acc[i][j] = (f32x4){0.f, 0.f, 0.f, 0.f};

    const int lrow = lane >> 2;
    const int gck  = (lane & 3) ^ ((lane >> 3) & 3);
    const int r15 = lane & 15;
    const int hi16 = lane >> 4;
    const int rck = (hi16 ^ ((r15 >> 1) & 3)) * 8;

    for (int k0 = 0; k0 < K; k0 += 32) {
#pragma unroll
        for (int s = 0; s < 2; ++s) {                  // W: 256 rows
            const int rbase = w * 32 + s * 16;
            const size_t gW = (size_t)(rbase + lrow) * K + k0 + gck * 8;
            gl_lds16(Wh_ + gW, sWhi + rbase * 32);
            gl_lds16(Wl_ + gW, sWlo + rbase * 32);
        }
        {                                              // A: 128 rows
            const int rbase = w * 16;
            const size_t gA = (size_t)(row0 + rbase + lrow) * K + k0 + gck * 8;
            gl_lds16(Ah + gA, sAhi + rbase * 32);
            gl_lds16(Al + gA, sAlo + rbase * 32);
        }
        __syncthreads();

        short8 ah[4], al[4], wh[4], wl[4];
#pragma unroll
        for (int i = 0; i < 4; ++i) {
            const int offA = (wm + i * 16 + r15) * 32 + rck;
            ah[i] = *(const short8*)(sAhi + offA);
            al[i] = *(const short8*)(sAlo + offA);
        }
#pragma unroll
        for (int j = 0; j < 4; ++j) {
            const int offW = (wn + j * 16 + r15) * 32 + rck;
            wh[j] = *(const short8*)(sWhi + offW);
            wl[j] = *(const short8*)(sWlo + offW);
        }
#pragma unroll
        for (int i = 0; i < 4; ++i)
#pragma unroll
            for (int j = 0; j < 4; ++j) {
                acc[i][j] = __builtin_amdgcn_mfma_f32_16x16x32_bf16(ah[i], wh[j], acc[i][j], 0, 0, 0);
                acc[i][j] = __builtin_amdgcn_mfma_f32_16x16x32_bf16(ah[i], wl[j], acc[i][j], 0, 0, 0);
                acc[i][j] = __builtin_amdgcn_mfma_f32_16x16x32_bf16(al[i], wh[j], acc[i][j], 0, 0, 0);
            }
        __syncthreads();
    }

    if (LNF == 0) {
#pragma unroll
        for (int j = 0; j < 4; ++j) {
            const int col = wn + j * 16 + r15;
            const float bb = bias[col];
#pragma unroll
            for (int i = 0; i < 4; ++i) {
                const int rowb = row0 + wm + i * 16 + hi16 * 4;
#pragma unroll
                for (int r = 0; r < 4; ++r)
                    Ch[(size_t)(rowb + r) * N + col] = f2b(acc[i][j][r] + bb);
            }
        }
    } else {
        // fused lrelu + row-LN. red[stat][lrow][cg], stat in {0,1}.
        float* red = (float*)sWhi;                 // 4 KB of the 16 KB buffer
        const int cg = w >> 1;
#pragma unroll
        for (int i = 0; i < 4; ++i) {
            float s1[4] = {0.f, 0.f, 0.f, 0.f};
            float s2[4] = {0.f, 0.f, 0.f, 0.f};
#pragma unroll
            for (int j = 0; j < 4; ++j) {
                const float bb = bias[wn + j * 16 + r15];
#pragma unroll
                for (int r = 0; r < 4; ++r) {
                    float v = acc[i][j][r] + bb;
                    float a = v > 0.f ? v : 0.2f * v;
                    s1[r] += a; s2[r] += a * a;
                }
            }
#pragma unroll
            for (int r = 0; r < 4; ++r) {
#pragma unroll
                for (int m = 8; m; m >>= 1) {
                    s1[r] += __shfl_xor(s1[r], m);
                    s2[r] += __shfl_xor(s2[r], m);
                }
            }
            if (r15 == 0) {
#pragma unroll
                for (int r = 0; r < 4; ++r) {
                    const int lr = wm + i * 16 + hi16 * 4 + r;
                    red[lr * 4 + cg] = s1[r];
                    red[(128 + lr) * 4 + cg] = s2[r];
                }
            }
        }
        __syncthreads();
#pragma unroll
        for (int i = 0; i < 4; ++i) {
#pragma unroll
            for (int r = 0; r < 4; ++r) {
                const int lr = wm + i * 16 + hi16 * 4 + r;
                float m = (red[lr * 4 + 0] + red[lr * 4 + 1] +
                           red[lr * 4 + 2] + red[lr * 4 + 3]) * (1.f / 256.f);
                float e2 = (red[(128 + lr) * 4 + 0] + red[(128 + lr) * 4 + 1] +
                            red[(128 + lr) * 4 + 2] + red[(128 + lr) * 4 + 3]) * (1.f / 256.f);
                float rstd = rsqrtf(e2 - m * m + 1e-5f);
                const size_t grow = (size_t)(row0 + lr);
#pragma unroll
                for (int j = 0; j < 4; ++j) {
                    const int col = wn + j * 16 + r15;
                    float v = acc[i][j][r] + bias[col];
                    float a = v > 0.f ? v : 0.2f * v;
                    Ch[grow * N + col] = f2b((a - m) * rstd * lng[col] + lnb[col]);
                }
            }
        }
    }
}

// ======== gemm3n: node-projection batched GEMM, 5-way (single dispatch) =====
// y = blockIdx.y in 0..4: W = Whi/Wlo + y*N*K; bias/out from arg struct.
// Plane-split A, M-guarded (per-lane source clamp).
struct G3N { const float* bias[5]; u32* out[5]; };
__global__ __launch_bounds__(512, 4)
void gemm3n(const u16* __restrict__ Ah, const u16* __restrict__ Al,
            const u16* __restrict__ Whi, const u16* __restrict__ Wlo,
            G3N a, int M, int K)
{
    constexpr int N = 256;
    __shared__ u16 sAhi[128 * 32];
    __shared__ u16 sAlo[128 * 32];
    __shared__ u16 sWhi[256 * 32];
    __shared__ u16 sWlo[256 * 32];

    const int tid  = threadIdx.x;
    const int lane = tid & 63;
    const int w    = tid >> 6;
    const int wm   = (w & 1) * 64;
    const int wn   = (w >> 1) * 64;
    const int row0 = blockIdx.x * 128;
    const int y    = blockIdx.y;
    const float* bias = a.bias[y];
    const u16* Wh = Whi + (size_t)y * N * K;
    const u16* Wl = Wlo + (size_t)y * N * K;
    u32* Cy = a.out[y];

    f32x4 acc[4][4];
#pragma unroll
    for (int i = 0; i < 4; ++i)
#pragma unroll
        for (int j = 0; j < 4; ++j) acc[i][j] = (f32x4){0.f, 0.f, 0.f, 0.f};

    const int lrow = lane >> 2;
    const int gck  = (lane & 3) ^ ((lane >> 3) & 3);
    const int r15 = lane & 15;
    const int rck = ((lane >> 4) ^ ((r15 >> 1) & 3)) * 8;

    for (int k0 = 0; k0 < K; k0 += 32) {
#pragma unroll
        for (int s = 0; s < 2; ++s) {
            const int rbase = w * 32 + s * 16;
            const size_t gW = (size_t)(rbase + lrow) * K + k0 + gck * 8;
            gl_lds16(Wh + gW, sWhi + rbase * 32);
            gl_lds16(Wl + gW, sWlo + rbase * 32);
        }
        {
            const int rbase = w * 16;
            int arow = row0 + rbase + lrow;
            if (arow >= M) arow = M - 1;               // per-lane source clamp
            const size_t gA = (size_t)arow * K + k0 + gck * 8;
            gl_lds16(Ah + gA, sAhi + rbase * 32);
            gl_lds16(Al + gA, sAlo + rbase * 32);
        }
        __syncthreads();

        short8 ah[4], al[4], wh[4], wl[4];
#pragma unroll
        for (int i = 0; i < 4; ++i) {
            const int offA = (wm + i * 16 + r15) * 32 + rck;
            ah[i] = *(const short8*)(sAhi + offA);
            al[i] = *(const short8*)(sAlo + offA);
        }
#pragma unroll
        for (int j = 0; j < 4; ++j) {
            const int offW = (wn + j * 16 + r15) * 32 + rck;
            wh[j] = *(const short8*)(sWhi + offW);
            wl[j] = *(const short8*)(sWlo + offW);
        }
#pragma unroll
        for (int i = 0; i < 4; ++i)
#pragma unroll
            for (int j = 0; j < 4; ++j) {
                acc[i][j] = __builtin_amdgcn_mfma_f32_16x16x32_bf16(ah[i], wh[j], acc[i][j], 0, 0, 0);
                acc[i][j] = __builtin_amdgcn_mfma_f32_16x16x32_bf16(ah[i], wl[j], acc[i][j], 0, 0, 0);
                acc[i][j] = __builtin_amdgcn_mfma_f32_16x16x32_bf16(al[i], wh[j], acc[i][j], 0, 0, 0);
            }
        __syncthreads();
    }

#pragma unroll
    for (int j = 0; j < 4; ++j) {
        const int col = wn + j * 16 + r15;
        const float bb = bias[col];
#pragma unroll
        for (int i = 0; i < 4; ++i) {
            const int rowb = row0 + wm + i * 16 + (lane >> 4) * 4;
#pragma unroll
            for (int r = 0; r < 4; ++r) {
                const int row = rowb + r;
                if (row < M)
                    Cy[(size_t)row * N + col] = packf(acc[i][j][r] + bb);
            }
        }
    }
}

// ---------------- x fp32 -> hi/lo bf16 planes ----------------
__global__ void pack_x(const float* __restrict__ x, u16* __restrict__ xh,
                       u16* __restrict__ xl, int n)
{
    int i = blockIdx.x * 256 + threadIdx.x;
    if (i < n) {
        float v = x[i];
        u16 h = f2b(v);
        xh[i] = h;
        xl[i] = f2b(v - b2f(h));
    }
}

// ---------------- weight conversions in ONE launch (21 regions of DD) -------
struct WcvA { const float* s[21]; u16* h[21]; u16* l[21]; };
__global__ __launch_bounds__(256)
void wconv_all(WcvA a, int n)
{
    int i = blockIdx.x * 256 + threadIdx.x;
    if (i >= n) return;
    int r = i >> 16;
    int o = i & 65535;
    float v = a.s[r][o];
    u16 hh = f2b(v);
    a.h[r][o] = hh;
    if (a.l[r]) a.l[r][o] = f2b(v - b2f(hh));
}

// ---------------- Wc = Wq1 @ Wff0 (fp32), bc = bq1 + Wq1 @ bff --------------
__global__ __launch_bounds__(256)
void wcomb(const float* __restrict__ Wq1, const float* __restrict__ Wff0,
           const float* __restrict__ bff, const float* __restrict__ bq1,
           u16* __restrict__ wch, u16* __restrict__ wcl, float* __restrict__ bc)
{
    const int o = blockIdx.x;
    const int j = threadIdx.x;
    const float* wq = Wq1 + (size_t)o * 256;
    float s = 0.f;
    for (int k = 0; k < 256; ++k)
        s = fmaf(wq[k], Wff0[(size_t)k * 256 + j], s);
    u16 h = f2b(s);
    wch[(size_t)o * 256 + j] = h;
    wcl[(size_t)o * 256 + j] = f2b(s - b2f(h));
    float p = wq[j] * bff[j];
    p = wred(p);
    __shared__ float ps[4];
    if ((j & 63) == 0) ps[j >> 6] = p;
    __syncthreads();
    if (j == 0) bc[o] = bq1[o] + ps[0] + ps[1] + ps[2] + ps[3];
}

// ---------------- segment-softmax ----------------
__global__ void seg_init(u32* __restrict__ amax, float* __restrict__ denom, int n)
{
    int i = blockIdx.x * 256 + threadIdx.x;
    if (i < n) { amax[i] = 0u; denom[i] = 0.f; }
}

template<typename TQ, int MODE>
__global__ __launch_bounds__(256)
void attn_alpha(const int* __restrict__ src, const int* __restrict__ dst,
                const TQ* __restrict__ qn, const u32* __restrict__ kn,
                float* __restrict__ alpha, u32* __restrict__ amax, int E)
{
    int e = blockIdx.x * 4 + (threadIdx.x >> 6);
    int lane = threadIdx.x & 63;
    if (e >= E) return;
    int s = src[e], d = dst[e];
    const TQ* qp = MODE ? (qn + (size_t)e * D) : (qn + (size_t)d * D);
    const u32* kp = kn + (size_t)s * D;
    float dot = 0.f;
#pragma unroll
    for (int j = 0; j < 4; ++j)
        dot += ld1(qp + lane * 4 + j) * unpackf(kp[lane * 4 + j]);
    dot = wred(dot);
    if (lane == 0) {
        alpha[e] = dot;
        atomicMax(amax + d, f2ord(dot));
    }
}

__global__ void seg_exp(const int* __restrict__ dst, const float* __restrict__ alpha,
                        const u32* __restrict__ amax, float* __restrict__ ebuf,
                        float* __restrict__ denom, int E)
{
    int e = blockIdx.x * 256 + threadIdx.x;
    if (e >= E) return;
    int d = dst[e];
    float ex = expf(alpha[e] - ord2f(amax[d]));
    ebuf[e] = ex;
    atomicAdd(denom + d, ex);
}

// ---------------- out(local, hi/lo planes) = LN(q + attn*v[src]) ----------------
template<typename TQ, int MODE>
__global__ __launch_bounds__(256)
void attn_out_ln(const int* __restrict__ src, const int* __restrict__ dst,
                 const TQ* __restrict__ qn, const u32* __restrict__ vn,
                 const float* __restrict__ ebuf, const float* __restrict__ denom,
                 const float* __restrict__ g, const float* __restrict__ bb,
                 u16* __restrict__ oh, u16* __restrict__ ol, int e0, int cm)
{
    int le = blockIdx.x * 4 + (threadIdx.x >> 6);
    int lane = threadIdx.x & 63;
    if (le >= cm) return;
    int ge = e0 + le;
    int s = src[ge], d = dst[ge];
    float attn = ebuf[ge] / denom[d];
    const TQ* qp = MODE ? (qn + (size_t)ge * D) : (qn + (size_t)d * D);
    const u32* vp = vn + (size_t)s * D;
    int d0 = lane * 4;
    float a0 = ld1(qp + d0 + 0) + attn * unpackf(vp[d0 + 0]);
    float a1 = ld1(qp + d0 + 1) + attn * unpackf(vp[d0 + 1]);
    float a2 = ld1(qp + d0 + 2) + attn * unpackf(vp[d0 + 2]);
    float a3 = ld1(qp + d0 + 3) + attn * unpackf(vp[d0 + 3]);
    float mean = wred(a0 + a1 + a2 + a3) * (1.f / D);
    float c0 = a0 - mean, c1 = a1 - mean, c2 = a2 - mean, c3 = a3 - mean;
    float var = wred(c0 * c0 + c1 * c1 + c2 * c2 + c3 * c3) * (1.f / D);
    float rstd = rsqrtf(var + 1e-5f);
    float t0 = c0 * rstd * g[d0 + 0] + bb[d0 + 0];
    float t1 = c1 * rstd * g[d0 + 1] + bb[d0 + 1];
    float t2 = c2 * rstd * g[d0 + 2] + bb[d0 + 2];
    float t3 = c3 * rstd * g[d0 + 3] + bb[d0 + 3];
    size_t base = (size_t)le * D + d0;
    ushort4 ph, pl;
    ph.x = f2b(t0); pl.x = f2b(t0 - b2f(ph.x));
    ph.y = f2b(t1); pl.y = f2b(t1 - b2f(ph.y));
    ph.z = f2b(t2); pl.z = f2b(t2 - b2f(ph.z));
    ph.w = f2b(t3); pl.w = f2b(t3 - b2f(ph.w));
    *(ushort4*)(oh + base) = ph;
    *(ushort4*)(ol + base) = pl;
}

// ---------------- out[e0+le] = dot(LN(h+q), Wvec) + bvec (u16 h, u16 q) ----------------
__global__ __launch_bounds__(256)
void final_k(const u16* __restrict__ hp, const u16* __restrict__ qp,
             const float* __restrict__ gfin, const float* __restrict__ bfin,
             const float* __restrict__ wvec, const float* __restrict__ bvec,
             float* __restrict__ out, int e0, int cm)
{
    int le = blockIdx.x * 4 + (threadIdx.x >> 6);
    int lane = threadIdx.x & 63;
    if (le >= cm) return;
    size_t base = (size_t)le * D + lane * 4;
    ushort4 hv = *(const ushort4*)(hp + base);
    ushort4 qv = *(const ushort4*)(qp + base);
    float a0 = b2f(hv.x) + b2f(qv.x);
    float a1 = b2f(hv.y) + b2f(qv.y);
    float a2 = b2f(hv.z) + b2f(qv.z);
    float a3 = b2f(hv.w) + b2f(qv.w);
    float mean = wred(a0 + a1 + a2 + a3) * (1.f / D);
    float c0 = a0 - mean, c1 = a1 - mean, c2 = a2 - mean, c3 = a3 - mean;
    float var = wred(c0 * c0 + c1 * c1 + c2 * c2 + c3 * c3) * (1.f / D);
    float rstd = rsqrtf(var + 1e-5f);
    int d0 = lane * 4;
    float t0 = c0 * rstd * gfin[d0 + 0] + bfin[d0 + 0];
    float t1 = c1 * rstd * gfin[d0 + 1] + bfin[d0 + 1];
    float t2 = c2 * rstd * gfin[d0 + 2] + bfin[d0 + 2];
    float t3 = c3 * rstd * gfin[d0 + 3] + bfin[d0 + 3];
    float part = t0 * wvec[d0 + 0] + t1 * wvec[d0 + 1] +
                 t2 * wvec[d0 + 2] + t3 * wvec[d0 + 3];
    part = wred(part);
    if (lane == 0) out[e0 + le] = part + bvec[0];
}

extern "C" void kernel_launch(void* const* d_in, const int* in_sizes, int n_in,
                              void* d_out, int out_size, void* d_ws, size_t ws_size,
                              hipStream_t stream)
{
    const int*   ei   = (const int*)d_in[0];
    const float* x    = (const float*)d_in[1];
    const float* Wq   = (const float*)d_in[2];
    const float* bq   = (const float*)d_in[3];
    const float* Wk   = (const float*)d_in[4];
    const float* bk   = (const float*)d_in[5];
    const float* Wv   = (const float*)d_in[6];
    const float* bv   = (const float*)d_in[7];
    const float* Wff  = (const float*)d_in[8];
    const float* bff  = (const float*)d_in[9];
    const float* ga   = (const float*)d_in[10];
    const float* ba   = (const float*)d_in[11];
    const float* gf   = (const float*)d_in[12];
    const float* bf   = (const float*)d_in[13];
    const float* gfin = (const float*)d_in[14];
    const float* bfin = (const float*)d_in[15];
    const float* W3   = (const float*)d_in[16];
    const float* b3   = (const float*)d_in[17];
    const float* W4   = (const float*)d_in[18];
    const float* b4   = (const float*)d_in[19];
    const float* W5   = (const float*)d_in[20];
    const float* b5   = (const float*)d_in[21];
    const float* Wvec = (const float*)d_in[22];
    const float* bvec = (const float*)d_in[23];

    const int E  = in_sizes[0] / 2;     // 160000
    const int Nn = in_sizes[1] / D;
    const int* src = ei;
    const int* dst = ei + E;

    // ---- workspace carve: fixed region ----
    char* base = (char*)d_ws;
    size_t off = 0;
    auto take = [&](size_t bytes) -> void* {
        off = (off + 255) & ~(size_t)255;
        void* r = base + off;
        off += bytes;
        return r;
    };
    u32*   nKV1 = (u32*)take((size_t)2 * Nn * D * 4);    // packed K1,V1
    u16*   q1  = (u16*)take((size_t)E * D * 2);          // hi-only bf16
    float* alpha = (float*)take((size_t)E * 4);
    float* ebuf  = (float*)take((size_t)E * 4);
    u32*   amax  = (u32*)take((size_t)2 * Nn * 4);       // layer0 | layer1
    float* denom = (float*)take((size_t)2 * Nn * 4);
    u16* wnh = (u16*)take((size_t)5 * D * D * 2);        // node weights hi (stacked)
    u16* wnl = (u16*)take((size_t)5 * D * D * 2);        // node weights lo
    u16* wff1h = (u16*)take((size_t)D * D * 2); u16* wff1l = (u16*)take((size_t)D * D * 2);
    u16* wch = (u16*)take((size_t)D * D * 2);            // composed Wq1@Wff0 hi
    u16* wcl = (u16*)take((size_t)D * D * 2);            // composed lo
    float* bc = (float*)take((size_t)D * 4);             // composed bias
    u16* w3h = (u16*)take((size_t)3 * D * D * 2);
    u16* w4h = (u16*)take((size_t)9 * D * D * 2);
    u16* w5h = (u16*)take((size_t)3 * D * D * 2);

    // ---- adaptive chunk ----
    const size_t nodeB = (size_t)4 * Nn * D * 4;
    size_t rem = ws_size > off + 8192 ? ws_size - off - 8192 : 0;
    size_t cmA = rem / 4096;
    size_t cmB = rem > nodeB ? (rem - nodeB) / 2048 : 0;
    size_t CMs = (cmA * 2048 >= nodeB) ? cmA : cmB;
    CMs = (CMs / 128) * 128;
    if (CMs > (size_t)E) CMs = E;
    if (CMs > 32768) CMs = 32768;       // one co-residency round for gemm2
    if (CMs < 128) CMs = 128;
    const int CM = (int)CMs;

    // chunk planes: 4 slots of CM*D u16. c1h/c1l = slots 0,1;
    // c4 = slots 0-2 (CM*3D, clobbers c1 after it is dead), c5 = slot 3.
    u16* cpl = (u16*)take((size_t)CM * D * 2 * 4);
    u16* c1h = cpl;
    u16* c1l = cpl + (size_t)CM * D;
    u16* c4  = cpl;                                   // CM*3D u16
    u16* c5  = cpl + (size_t)3 * CM * D;              // CM*D u16
    size_t zoneB = (size_t)CM * 2048 > nodeB ? (size_t)CM * 2048 : nodeB;
    char* zone = (char*)take(zoneB);
    u16* c2n = (u16*)zone;                            // CM*D u16 (pass 2)
    u16* c3  = (u16*)(zone + (size_t)CM * D * 2);     // CM*3D u16 (pass 2)
    u16* xph = (u16*)zone;                            // Nn*D hi plane (pre)
    u16* xpl = xph + (size_t)Nn * D;                  // Nn*D lo plane
    u32* zQKV = (u32*)(zone + (size_t)Nn * D * 4);    // packed Q0,K0,V0
    u32* zQ0 = zQKV;
    u32* zK0 = zQKV + (size_t)Nn * D;
    u32* zV0 = zQKV + (size_t)2 * Nn * D;
    u32* nK1 = nKV1;
    u32* nV1 = nKV1 + (size_t)Nn * D;

    dim3 blk(256);
    dim3 blk2(512);
    int gridE4  = (E + 3) / 4;
    int gridE   = (E + 255) / 256;
    const int DD = D * D;               // 65536 = 2^16

    // ---- pack x + single up-front softmax-state init (both layers) ----
    pack_x<<<(Nn * D + 255) / 256, 256, 0, stream>>>(x, xph, xpl, Nn * D);
    seg_init<<<(2 * Nn + 255) / 256, 256, 0, stream>>>(amax, denom, 2 * Nn);

    // ---- single-launch weight conversion (21 regions) ----
    WcvA wa;
    const float* ws_[21] = {Wq, Wk, Wv, Wk + DD, Wv + DD, Wff + DD,
                            W3, W3 + DD, W3 + 2 * DD,
                            W4, W4 + DD, W4 + 2 * DD, W4 + 3 * DD, W4 + 4 * DD,
                            W4 + 5 * DD, W4 + 6 * DD, W4 + 7 * DD, W4 + 8 * DD,
                            W5, W5 + DD, W5 + 2 * DD};
    u16* wh_[21] = {wnh, wnh + DD, wnh + 2 * DD, wnh + 3 * DD, wnh + 4 * DD, wff1h,
                    w3h, w3h + DD, w3h + 2 * DD,
                    w4h, w4h + DD, w4h + 2 * DD, w4h + 3 * DD, w4h + 4 * DD,
                    w4h + 5 * DD, w4h + 6 * DD, w4h + 7 * DD, w4h + 8 * DD,
                    w5h, w5h + DD, w5h + 2 * DD};
    u16* wl_[21] = {wnl, wnl + DD, wnl + 2 * DD, wnl + 3 * DD, wnl + 4 * DD, wff1l,
                    nullptr, nullptr, nullptr,
                    nullptr, nullptr, nullptr, nullptr, nullptr,
                    nullptr, nullptr, nullptr, nullptr,
                    nullptr, nullptr, nullptr};
    for (int r = 0; r < 21; ++r) { wa.s[r] = ws_[r]; wa.h[r] = wh_[r]; wa.l[r] = wl_[r]; }
    wconv_all<<<(21 * DD) / 256, 256, 0, stream>>>(wa, 21 * DD);

    // ---- compose pass-1 weights: Wc = Wq1 @ Wff0, bc = bq1 + Wq1 @ bff ----
    wcomb<<<256, 256, 0, stream>>>(Wq + DD, Wff, bff, bq + D, wch, wcl, bc);

    // ---- node projections: all 5 in one batched dispatch ----
    int gN = (Nn + 127) / 128;
    G3N g3;
    g3.bias[0] = bq;     g3.out[0] = zQ0;
    g3.bias[1] = bk;     g3.out[1] = zK0;
    g3.bias[2] = bv;     g3.out[2] = zV0;
    g3.bias[3] = bk + D; g3.out[3] = nK1;
    g3.bias[4] = bv + D; g3.out[4] = nV1;
    gemm3n<<<dim3(gN, 5), blk2, 0, stream>>>(xph, xpl, wnh, wnl, g3, Nn, D);

    // ---- layer-0 segment softmax ----
    attn_alpha<u32, 0><<<gridE4, blk, 0, stream>>>(src, dst, zQ0, zK0, alpha, amax, E);
    seg_exp<<<gridE, 256, 0, stream>>>(dst, alpha, amax, ebuf, denom, E);

    // ---- pass 1 (chunked): attnLN0 -> (Wq1@Wff0 composed) -> q1 ----
    for (int e0 = 0; e0 < E; e0 += CM) {
        int cm = E - e0 < CM ? E - e0 : CM;
        int gE4 = (cm + 3) / 4;
        dim3 gD3(cm / 128);
        attn_out_ln<u32, 0><<<gE4, blk, 0, stream>>>(src, dst, zQ0, zV0, ebuf, denom,
                                                     ga, ba, c1h, c1l, e0, cm);
        gemm3w<0><<<gD3, blk2, 0, stream>>>(c1h, c1l, wch, wcl, bc,
                                            (const float*)nullptr, (const float*)nullptr,
                                            q1 + (size_t)e0 * D, cm, D);
    }

    // ---- layer-1 segment softmax (state pre-initialized at amax+Nn) ----
    attn_alpha<u16, 1><<<gridE4, blk, 0, stream>>>(src, dst, q1, nK1, alpha,
                                                   amax + Nn, E);
    seg_exp<<<gridE, 256, 0, stream>>>(dst, alpha, amax + Nn, ebuf, denom + Nn, E);

    // ---- pass 2 (chunked) ----
    for (int e0 = 0; e0 < E; e0 += CM) {
        int cm = E - e0 < CM ? E - e0 : CM;
        int gE4 = (cm + 3) / 4;
        dim3 gD3(cm / 128);
        dim3 g2a(cm / 128, (3 * D) / 256);
        dim3 g2b(cm / 128, D / 256);
        attn_out_ln<u16, 1><<<gE4, blk, 0, stream>>>(src, dst, q1, nV1, ebuf,
                                                     denom + Nn,
                                                     ga + D, ba + D, c1h, c1l, e0, cm);
        // Wff1 GEMM with fused lrelu + LN epilogue -> c2n
        gemm3w<1><<<gD3, blk2, 0, stream>>>(c1h, c1l, wff1h, wff1l, bff + D,
                                            gf, bf, c2n, cm, D);
        gemm2<1><<<g2a, blk2, 0, stream>>>(c2n, w3h, b3, c3, cm, 3 * D, D);
        gemm2<1><<<g2a, blk2, 0, stream>>>(c3, w4h, b4, c4, cm, 3 * D, 3 * D);
        gemm2<0><<<g2b, blk2, 0, stream>>>(c4, w5h, b5, c5, cm, D, 3 * D);
        final_k<<<gE4, blk, 0, stream>>>(c5, c2n, gfin, bfin, Wvec, bvec,
                                         (float*)d_out, e0, cm);
    }
}

// Round 10
// 1179.804 us; speedup vs baseline: 1.0939x; 1.0331x over previous
//
#include <hip/hip_runtime.h>

#define D 256

typedef unsigned short u16;
typedef unsigned int u32;
typedef __attribute__((ext_vector_type(8))) short short8;
typedef __attribute__((ext_vector_type(4))) float f32x4;
typedef __attribute__((ext_vector_type(16))) float f32x16;

// ---------------- bf16 <-> f32, split-pack ----------------
__device__ __forceinline__ float b2f(u16 u) {
    return __uint_as_float(((u32)u) << 16);
}
__device__ __forceinline__ u16 f2b(float f) {
    u32 u = __float_as_uint(f);
    return (u16)((u + 0x7FFFu + ((u >> 16) & 1u)) >> 16);  // RNE
}
__device__ __forceinline__ u32 packf(float v) {
    u16 h = f2b(v);
    u16 l = f2b(v - b2f(h));
    return ((u32)h << 16) | l;
}
__device__ __forceinline__ float unpackf(u32 p) {
    return b2f((u16)(p >> 16)) + b2f((u16)(p & 0xffffu));
}
template<typename T> __device__ __forceinline__ float ld1(const T* p);
template<> __device__ __forceinline__ float ld1<u16>(const u16* p) { return b2f(*p); }
template<> __device__ __forceinline__ float ld1<u32>(const u32* p) { return unpackf(*p); }

__device__ __forceinline__ float wred(float v) {
#pragma unroll
    for (int m = 32; m; m >>= 1) v += __shfl_xor(v, m);
    return v;
}

// async global(16B/lane) -> LDS (wave-uniform base + lane*16)
__device__ __forceinline__ void gl_lds16(const u16* g, u16* l) {
    __builtin_amdgcn_global_load_lds(
        (__attribute__((address_space(1))) void*)(u16*)g,
        (__attribute__((address_space(3))) void*)l, 16, 0, 0);
}

// ======== gemm2: single-term MFMA GEMM, R2-verified config (locked) ========
// C = act(A[M,K] @ W[N,K]^T + b). A bf16 u16; W hi-plane u16.
// 128x256 tile, single 48KB buffer, 2 barriers/step, 3 blocks/CU. BK=64.
// Conflict-free swizzle key(r) = (r&7) ^ ((r>>3)&3) (measured: conflicts=0).
// R3-R5: dbuf variants all regressed; R8: fused final_k epilogue regressed.
// This is the locked local optimum. M%128==0, N%256==0, K%64==0.
template<int ACT>
__global__ __launch_bounds__(512, 4)
void gemm2(const u16* __restrict__ A, const u16* __restrict__ Whi,
           const float* __restrict__ bias, u16* __restrict__ C,
           int M, int N, int K)
{
    __shared__ u16 sA[128 * 64];       // 16 KB
    __shared__ u16 sWh[256 * 64];      // 32 KB

    const int tid  = threadIdx.x;
    const int lane = tid & 63;
    const int w    = tid >> 6;             // wave 0..7
    const int wm   = (w & 1) * 64;
    const int wn   = (w >> 1) * 64;
    const int row0 = blockIdx.x * 128;
    const int col0 = blockIdx.y * 256;

    f32x16 acc[2][2];
#pragma unroll
    for (int i = 0; i < 2; ++i)
#pragma unroll
        for (int j = 0; j < 2; ++j)
#pragma unroll
            for (int r = 0; r < 16; ++r) acc[i][j][r] = 0.f;

    const int r31   = lane & 31;
    const int khalf = lane >> 5;
    const int skey  = (r31 & 7) ^ ((r31 >> 3) & 3);
    const int l8r = lane >> 3;
    const int l8c = lane & 7;

    for (int k0 = 0; k0 < K; k0 += 64) {
#pragma unroll
        for (int s = 0; s < 4; ++s) {
            const int rbase = w * 32 + s * 8;
            const int row = rbase + l8r;
            const int gch = l8c ^ (row & 7) ^ s;
            const size_t gW = (size_t)(col0 + row) * K + k0 + gch * 8;
            gl_lds16(Whi + gW, sWh + rbase * 64);
        }
#pragma unroll
        for (int s = 0; s < 2; ++s) {
            const int rbase = w * 16 + s * 8;
            const int row = rbase + l8r;
            const int gch = l8c ^ (row & 7) ^ ((w * 2 + s) & 3);
            const size_t gA = (size_t)(row0 + row) * K + k0 + gch * 8;
            gl_lds16(A + gA, sA + rbase * 64);
        }
        __syncthreads();

#pragma unroll
        for (int w4 = 0; w4 < 4; ++w4) {
            const int slot = ((w4 * 2 + khalf) ^ skey) * 8;
            short8 af[2], wf[2];
#pragma unroll
            for (int i = 0; i < 2; ++i)
                af[i] = *(const short8*)(sA + (wm + i * 32 + r31) * 64 + slot);
#pragma unroll
            for (int j = 0; j < 2; ++j)
                wf[j] = *(const short8*)(sWh + (wn + j * 32 + r31) * 64 + slot);
#pragma unroll
            for (int i = 0; i < 2; ++i)
#pragma unroll
                for (int j = 0; j < 2; ++j)
                    acc[i][j] = __builtin_amdgcn_mfma_f32_32x32x16_bf16(af[i], wf[j], acc[i][j], 0, 0, 0);
        }
        __syncthreads();
    }

#pragma unroll
    for (int j = 0; j < 2; ++j) {
        const int col = col0 + wn + j * 32 + r31;
        const float bb = bias[col];
#pragma unroll
        for (int i = 0; i < 2; ++i) {
            const int rowb = row0 + wm + i * 32 + 4 * khalf;
#pragma unroll
            for (int reg = 0; reg < 16; ++reg) {
                const int row = rowb + (reg & 3) + 8 * (reg >> 2);
                float v = acc[i][j][reg] + bb;
                if (ACT) v = v > 0.f ? v : 0.2f * v;
                C[(size_t)row * N + col] = f2b(v);
            }
        }
    }
}

// ======== gemm3w: 3-term split MFMA GEMM, plane-split A, N=256 sweep ========
// C = A @ W^T + b with A = Ah + Al, W = Wh + Wl (3-term: hh + hl + lh).
// 16x16x32, BK=32, 128x256 block tile -> each block owns COMPLETE rows.
// LNF=0: epilogue writes hi-only bf16 (bias only).
// LNF=1: fused lrelu + row-LayerNorm epilogue.
// M%128==0, K%32==0.
template<int LNF>
__global__ __launch_bounds__(512, 4)
void gemm3w(const u16* __restrict__ Ah, const u16* __restrict__ Al,
            const u16* __restrict__ Wh_, const u16* __restrict__ Wl_,
            const float* __restrict__ bias,
            const float* __restrict__ lng, const float* __restrict__ lnb,
            u16* __restrict__ Ch, int M, int K)
{
    constexpr int N = 256;
    __shared__ u16 sAhi[128 * 32];
    __shared__ u16 sAlo[128 * 32];
    __shared__ u16 sWhi[256 * 32];
    __shared__ u16 sWlo[256 * 32];

    const int tid  = threadIdx.x;
    const int lane = tid & 63;
    const int w    = tid >> 6;
    const int wm   = (w & 1) * 64;
    const int wn   = (w >> 1) * 64;
    const int row0 = blockIdx.x * 128;

    f32x4 acc[4][4];
#pragma unroll
    for (int i = 0; i < 4; ++i)
#pragma unroll
        for (int j = 0; j < 4; ++j) acc[i][j] = (f32x4){0.f, 0.f, 0.f, 0.f};

    const int lrow = lane >> 2;
    const int gck  = (lane & 3) ^ ((lane >> 3) & 3);
    const int r15 = lane & 15;
    const int hi16 = lane >> 4;
    const int rck = (hi16 ^ ((r15 >> 1) & 3)) * 8;

    for (int k0 = 0; k0 < K; k0 += 32) {
#pragma unroll
        for (int s = 0; s < 2; ++s) {                  // W: 256 rows
            const int rbase = w * 32 + s * 16;
            const size_t gW = (size_t)(rbase + lrow) * K + k0 + gck * 8;
            gl_lds16(Wh_ + gW, sWhi + rbase * 32);
            gl_lds16(Wl_ + gW, sWlo + rbase * 32);
        }
        {                                              // A: 128 rows
            const int rbase = w * 16;
            const size_t gA = (size_t)(row0 + rbase + lrow) * K + k0 + gck * 8;
            gl_lds16(Ah + gA, sAhi + rbase * 32);
            gl_lds16(Al + gA, sAlo + rbase * 32);
        }
        __syncthreads();

        short8 ah[4], al[4], wh[4], wl[4];
#pragma unroll
        for (int i = 0; i < 4; ++i) {
            const int offA = (wm + i * 16 + r15) * 32 + rck;
            ah[i] = *(const short8*)(sAhi + offA);
            al[i] = *(const short8*)(sAlo + offA);
        }
#pragma unroll
        for (int j = 0; j < 4; ++j) {
            const int offW = (wn + j * 16 + r15) * 32 + rck;
            wh[j] = *(const short8*)(sWhi + offW);
            wl[j] = *(const short8*)(sWlo + offW);
        }
#pragma unroll
        for (int i = 0; i < 4; ++i)
#pragma unroll
            for (int j = 0; j < 4; ++j) {
                acc[i][j] = __builtin_amdgcn_mfma_f32_16x16x32_bf16(ah[i], wh[j], acc[i][j], 0, 0, 0);
                acc[i][j] = __builtin_amdgcn_mfma_f32_16x16x32_bf16(ah[i], wl[j], acc[i][j], 0, 0, 0);
                acc[i][j] = __builtin_amdgcn_mfma_f32_16x16x32_bf16(al[i], wh[j], acc[i][j], 0, 0, 0);
            }
        __syncthreads();
    }

    if (LNF == 0) {
#pragma unroll
        for (int j = 0; j < 4; ++j) {
            const int col = wn + j * 16 + r15;
            const float bb = bias[col];
#pragma unroll
            for (int i = 0; i < 4; ++i) {
                const int rowb = row0 + wm + i * 16 + hi16 * 4;
#pragma unroll
                for (int r = 0; r < 4; ++r)
                    Ch[(size_t)(rowb + r) * N + col] = f2b(acc[i][j][r] + bb);
            }
        }
    } else {
        // fused lrelu + row-LN. red[stat][lrow][cg], stat in {0,1}.
        float* red = (float*)sWhi;                 // 4 KB of the 16 KB buffer
        const int cg = w >> 1;
#pragma unroll
        for (int i = 0; i < 4; ++i) {
            float s1[4] = {0.f, 0.f, 0.f, 0.f};
            float s2[4] = {0.f, 0.f, 0.f, 0.f};
#pragma unroll
            for (int j = 0; j < 4; ++j) {
                const float bb = bias[wn + j * 16 + r15];
#pragma unroll
                for (int r = 0; r < 4; ++r) {
                    float v = acc[i][j][r] + bb;
                    float a = v > 0.f ? v : 0.2f * v;
                    s1[r] += a; s2[r] += a * a;
                }
            }
#pragma unroll
            for (int r = 0; r < 4; ++r) {
#pragma unroll
                for (int m = 8; m; m >>= 1) {
                    s1[r] += __shfl_xor(s1[r], m);
                    s2[r] += __shfl_xor(s2[r], m);
                }
            }
            if (r15 == 0) {
#pragma unroll
                for (int r = 0; r < 4; ++r) {
                    const int lr = wm + i * 16 + hi16 * 4 + r;
                    red[lr * 4 + cg] = s1[r];
                    red[(128 + lr) * 4 + cg] = s2[r];
                }
            }
        }
        __syncthreads();
#pragma unroll
        for (int i = 0; i < 4; ++i) {
#pragma unroll
            for (int r = 0; r < 4; ++r) {
                const int lr = wm + i * 16 + hi16 * 4 + r;
                float m = (red[lr * 4 + 0] + red[lr * 4 + 1] +
                           red[lr * 4 + 2] + red[lr * 4 + 3]) * (1.f / 256.f);
                float e2 = (red[(128 + lr) * 4 + 0] + red[(128 + lr) * 4 + 1] +
                            red[(128 + lr) * 4 + 2] + red[(128 + lr) * 4 + 3]) * (1.f / 256.f);
                float rstd = rsqrtf(e2 - m * m + 1e-5f);
                const size_t grow = (size_t)(row0 + lr);
#pragma unroll
                for (int j = 0; j < 4; ++j) {
                    const int col = wn + j * 16 + r15;
                    float v = acc[i][j][r] + bias[col];
                    float a = v > 0.f ? v : 0.2f * v;
                    Ch[grow * N + col] = f2b((a - m) * rstd * lng[col] + lnb[col]);
                }
            }
        }
    }
}

// ======== gemm3n: node-projection batched GEMM, 5-way (single dispatch) =====
// y = blockIdx.y in 0..4: W = Whi/Wlo + y*N*K. Per-y output: packed u32
// (o32) OR hi-only bf16 (o16) — exactly one non-null. V outputs (y=2,4)
// are hi-only (R9->R10: halves v-gather bytes in attn_out_ln).
struct G3N { const float* bias[5]; u32* o32[5]; u16* o16[5]; };
__global__ __launch_bounds__(512, 4)
void gemm3n(const u16* __restrict__ Ah, const u16* __restrict__ Al,
            const u16* __restrict__ Whi, const u16* __restrict__ Wlo,
            G3N a, int M, int K)
{
    constexpr int N = 256;
    __shared__ u16 sAhi[128 * 32];
    __shared__ u16 sAlo[128 * 32];
    __shared__ u16 sWhi[256 * 32];
    __shared__ u16 sWlo[256 * 32];

    const int tid  = threadIdx.x;
    const int lane = tid & 63;
    const int w    = tid >> 6;
    const int wm   = (w & 1) * 64;
    const int wn   = (w >> 1) * 64;
    const int row0 = blockIdx.x * 128;
    const int y    = blockIdx.y;
    const float* bias = a.bias[y];
    const u16* Wh = Whi + (size_t)y * N * K;
    const u16* Wl = Wlo + (size_t)y * N * K;
    u32* C32 = a.o32[y];
    u16* C16 = a.o16[y];

    f32x4 acc[4][4];
#pragma unroll
    for (int i = 0; i < 4; ++i)
#pragma unroll
        for (int j = 0; j < 4; ++j) acc[i][j] = (f32x4){0.f, 0.f, 0.f, 0.f};

    const int lrow = lane >> 2;
    const int gck  = (lane & 3) ^ ((lane >> 3) & 3);
    const int r15 = lane & 15;
    const int rck = ((lane >> 4) ^ ((r15 >> 1) & 3)) * 8;

    for (int k0 = 0; k0 < K; k0 += 32) {
#pragma unroll
        for (int s = 0; s < 2; ++s) {
            const int rbase = w * 32 + s * 16;
            const size_t gW = (size_t)(rbase + lrow) * K + k0 + gck * 8;
            gl_lds16(Wh + gW, sWhi + rbase * 32);
            gl_lds16(Wl + gW, sWlo + rbase * 32);
        }
        {
            const int rbase = w * 16;
            int arow = row0 + rbase + lrow;
            if (arow >= M) arow = M - 1;               // per-lane source clamp
            const size_t gA = (size_t)arow * K + k0 + gck * 8;
            gl_lds16(Ah + gA, sAhi + rbase * 32);
            gl_lds16(Al + gA, sAlo + rbase * 32);
        }
        __syncthreads();

        short8 ah[4], al[4], wh[4], wl[4];
#pragma unroll
        for (int i = 0; i < 4; ++i) {
            const int offA = (wm + i * 16 + r15) * 32 + rck;
            ah[i] = *(const short8*)(sAhi + offA);
            al[i] = *(const short8*)(sAlo + offA);
        }
#pragma unroll
        for (int j = 0; j < 4; ++j) {
            const int offW = (wn + j * 16 + r15) * 32 + rck;
            wh[j] = *(const short8*)(sWhi + offW);
            wl[j] = *(const short8*)(sWlo + offW);
        }
#pragma unroll
        for (int i = 0; i < 4; ++i)
#pragma unroll
            for (int j = 0; j < 4; ++j) {
                acc[i][j] = __builtin_amdgcn_mfma_f32_16x16x32_bf16(ah[i], wh[j], acc[i][j], 0, 0, 0);
                acc[i][j] = __builtin_amdgcn_mfma_f32_16x16x32_bf16(ah[i], wl[j], acc[i][j], 0, 0, 0);
                acc[i][j] = __builtin_amdgcn_mfma_f32_16x16x32_bf16(al[i], wh[j], acc[i][j], 0, 0, 0);
            }
        __syncthreads();
    }

#pragma unroll
    for (int j = 0; j < 4; ++j) {
        const int col = wn + j * 16 + r15;
        const float bb = bias[col];
#pragma unroll
        for (int i = 0; i < 4; ++i) {
            const int rowb = row0 + wm + i * 16 + (lane >> 4) * 4;
#pragma unroll
            for (int r = 0; r < 4; ++r) {
                const int row = rowb + r;
                if (row < M) {
                    float v = acc[i][j][r] + bb;
                    if (C16) C16[(size_t)row * N + col] = f2b(v);
                    else     C32[(size_t)row * N + col] = packf(v);
                }
            }
        }
    }
}

// ---------------- x fp32 -> hi/lo bf16 planes ----------------
__global__ void pack_x(const float* __restrict__ x, u16* __restrict__ xh,
                       u16* __restrict__ xl, int n)
{
    int i = blockIdx.x * 256 + threadIdx.x;
    if (i < n) {
        float v = x[i];
        u16 h = f2b(v);
        xh[i] = h;
        xl[i] = f2b(v - b2f(h));
    }
}

// ---------------- weight conversions in ONE launch (21 regions of DD) -------
struct WcvA { const float* s[21]; u16* h[21]; u16* l[21]; };
__global__ __launch_bounds__(256)
void wconv_all(WcvA a, int n)
{
    int i = blockIdx.x * 256 + threadIdx.x;
    if (i >= n) return;
    int r = i >> 16;
    int o = i & 65535;
    float v = a.s[r][o];
    u16 hh = f2b(v);
    a.h[r][o] = hh;
    if (a.l[r]) a.l[r][o] = f2b(v - b2f(hh));
}

// ---------------- Wc = Wq1 @ Wff0 (fp32), bc = bq1 + Wq1 @ bff --------------
__global__ __launch_bounds__(256)
void wcomb(const float* __restrict__ Wq1, const float* __restrict__ Wff0,
           const float* __restrict__ bff, const float* __restrict__ bq1,
           u16* __restrict__ wch, u16* __restrict__ wcl, float* __restrict__ bc)
{
    const int o = blockIdx.x;
    const int j = threadIdx.x;
    const float* wq = Wq1 + (size_t)o * 256;
    float s = 0.f;
    for (int k = 0; k < 256; ++k)
        s = fmaf(wq[k], Wff0[(size_t)k * 256 + j], s);
    u16 h = f2b(s);
    wch[(size_t)o * 256 + j] = h;
    wcl[(size_t)o * 256 + j] = f2b(s - b2f(h));
    float p = wq[j] * bff[j];
    p = wred(p);
    __shared__ float ps[4];
    if ((j & 63) == 0) ps[j >> 6] = p;
    __syncthreads();
    if (j == 0) bc[o] = bq1[o] + ps[0] + ps[1] + ps[2] + ps[3];
}

// ---------------- segment-softmax state init (denom only) ----------------
__global__ void seg_init(float* __restrict__ denom, int n)
{
    int i = blockIdx.x * 256 + threadIdx.x;
    if (i < n) denom[i] = 0.f;
}

// ---------------- exp-direct segment softmax: ebuf = exp(q.k), denom += -----
// No max-subtraction: alpha ~ N(0, ~10) (sum of 256 small products), so
// exp stays far inside f32 range (overflow needs alpha > 87 ~= 8.7 sigma).
// Mathematically identical to max-subtracted softmax; removes the separate
// seg_exp kernel + alpha/amax buffers + ordered-max atomics.
template<typename TQ, int MODE>
__global__ __launch_bounds__(256)
void attn_alpha(const int* __restrict__ src, const int* __restrict__ dst,
                const TQ* __restrict__ qn, const u32* __restrict__ kn,
                float* __restrict__ ebuf, float* __restrict__ denom, int E)
{
    int e = blockIdx.x * 4 + (threadIdx.x >> 6);
    int lane = threadIdx.x & 63;
    if (e >= E) return;
    int s = src[e], d = dst[e];
    const TQ* qp = MODE ? (qn + (size_t)e * D) : (qn + (size_t)d * D);
    const u32* kp = kn + (size_t)s * D;
    float dot = 0.f;
#pragma unroll
    for (int j = 0; j < 4; ++j)
        dot += ld1(qp + lane * 4 + j) * unpackf(kp[lane * 4 + j]);
    dot = wred(dot);
    if (lane == 0) {
        float ex = expf(dot);
        ebuf[e] = ex;
        atomicAdd(denom + d, ex);
    }
}

// ---------------- out(local, hi/lo planes) = LN(q + attn*v[src]) ----------------
// v is hi-only bf16 (R10): halves the dominant gather in this kernel.
template<typename TQ, int MODE>
__global__ __launch_bounds__(256)
void attn_out_ln(const int* __restrict__ src, const int* __restrict__ dst,
                 const TQ* __restrict__ qn, const u16* __restrict__ vn,
                 const float* __restrict__ ebuf, const float* __restrict__ denom,
                 const float* __restrict__ g, const float* __restrict__ bb,
                 u16* __restrict__ oh, u16* __restrict__ ol, int e0, int cm)
{
    int le = blockIdx.x * 4 + (threadIdx.x >> 6);
    int lane = threadIdx.x & 63;
    if (le >= cm) return;
    int ge = e0 + le;
    int s = src[ge], d = dst[ge];
    float attn = ebuf[ge] / denom[d];
    const TQ* qp = MODE ? (qn + (size_t)ge * D) : (qn + (size_t)d * D);
    const u16* vp = vn + (size_t)s * D;
    int d0 = lane * 4;
    ushort4 vv = *(const ushort4*)(vp + d0);
    float a0 = ld1(qp + d0 + 0) + attn * b2f(vv.x);
    float a1 = ld1(qp + d0 + 1) + attn * b2f(vv.y);
    float a2 = ld1(qp + d0 + 2) + attn * b2f(vv.z);
    float a3 = ld1(qp + d0 + 3) + attn * b2f(vv.w);
    float mean = wred(a0 + a1 + a2 + a3) * (1.f / D);
    float c0 = a0 - mean, c1 = a1 - mean, c2 = a2 - mean, c3 = a3 - mean;
    float var = wred(c0 * c0 + c1 * c1 + c2 * c2 + c3 * c3) * (1.f / D);
    float rstd = rsqrtf(var + 1e-5f);
    float t0 = c0 * rstd * g[d0 + 0] + bb[d0 + 0];
    float t1 = c1 * rstd * g[d0 + 1] + bb[d0 + 1];
    float t2 = c2 * rstd * g[d0 + 2] + bb[d0 + 2];
    float t3 = c3 * rstd * g[d0 + 3] + bb[d0 + 3];
    size_t base = (size_t)le * D + d0;
    ushort4 ph, pl;
    ph.x = f2b(t0); pl.x = f2b(t0 - b2f(ph.x));
    ph.y = f2b(t1); pl.y = f2b(t1 - b2f(ph.y));
    ph.z = f2b(t2); pl.z = f2b(t2 - b2f(ph.z));
    ph.w = f2b(t3); pl.w = f2b(t3 - b2f(ph.w));
    *(ushort4*)(oh + base) = ph;
    *(ushort4*)(ol + base) = pl;
}

// ---------------- out[e0+le] = dot(LN(h+q), Wvec) + bvec (u16 h, u16 q) ----------------
__global__ __launch_bounds__(256)
void final_k(const u16* __restrict__ hp, const u16* __restrict__ qp,
             const float* __restrict__ gfin, const float* __restrict__ bfin,
             const float* __restrict__ wvec, const float* __restrict__ bvec,
             float* __restrict__ out, int e0, int cm)
{
    int le = blockIdx.x * 4 + (threadIdx.x >> 6);
    int lane = threadIdx.x & 63;
    if (le >= cm) return;
    size_t base = (size_t)le * D + lane * 4;
    ushort4 hv = *(const ushort4*)(hp + base);
    ushort4 qv = *(const ushort4*)(qp + base);
    float a0 = b2f(hv.x) + b2f(qv.x);
    float a1 = b2f(hv.y) + b2f(qv.y);
    float a2 = b2f(hv.z) + b2f(qv.z);
    float a3 = b2f(hv.w) + b2f(qv.w);
    float mean = wred(a0 + a1 + a2 + a3) * (1.f / D);
    float c0 = a0 - mean, c1 = a1 - mean, c2 = a2 - mean, c3 = a3 - mean;
    float var = wred(c0 * c0 + c1 * c1 + c2 * c2 + c3 * c3) * (1.f / D);
    float rstd = rsqrtf(var + 1e-5f);
    int d0 = lane * 4;
    float t0 = c0 * rstd * gfin[d0 + 0] + bfin[d0 + 0];
    float t1 = c1 * rstd * gfin[d0 + 1] + bfin[d0 + 1];
    float t2 = c2 * rstd * gfin[d0 + 2] + bfin[d0 + 2];
    float t3 = c3 * rstd * gfin[d0 + 3] + bfin[d0 + 3];
    float part = t0 * wvec[d0 + 0] + t1 * wvec[d0 + 1] +
                 t2 * wvec[d0 + 2] + t3 * wvec[d0 + 3];
    part = wred(part);
    if (lane == 0) out[e0 + le] = part + bvec[0];
}

extern "C" void kernel_launch(void* const* d_in, const int* in_sizes, int n_in,
                              void* d_out, int out_size, void* d_ws, size_t ws_size,
                              hipStream_t stream)
{
    const int*   ei   = (const int*)d_in[0];
    const float* x    = (const float*)d_in[1];
    const float* Wq   = (const float*)d_in[2];
    const float* bq   = (const float*)d_in[3];
    const float* Wk   = (const float*)d_in[4];
    const float* bk   = (const float*)d_in[5];
    const float* Wv   = (const float*)d_in[6];
    const float* bv   = (const float*)d_in[7];
    const float* Wff  = (const float*)d_in[8];
    const float* bff  = (const float*)d_in[9];
    const float* ga   = (const float*)d_in[10];
    const float* ba   = (const float*)d_in[11];
    const float* gf   = (const float*)d_in[12];
    const float* bf   = (const float*)d_in[13];
    const float* gfin = (const float*)d_in[14];
    const float* bfin = (const float*)d_in[15];
    const float* W3   = (const float*)d_in[16];
    const float* b3   = (const float*)d_in[17];
    const float* W4   = (const float*)d_in[18];
    const float* b4   = (const float*)d_in[19];
    const float* W5   = (const float*)d_in[20];
    const float* b5   = (const float*)d_in[21];
    const float* Wvec = (const float*)d_in[22];
    const float* bvec = (const float*)d_in[23];

    const int E  = in_sizes[0] / 2;     // 160000
    const int Nn = in_sizes[1] / D;
    const int* src = ei;
    const int* dst = ei + E;

    // ---- workspace carve: fixed region ----
    char* base = (char*)d_ws;
    size_t off = 0;
    auto take = [&](size_t bytes) -> void* {
        off = (off + 255) & ~(size_t)255;
        void* r = base + off;
        off += bytes;
        return r;
    };
    u32*   nK1 = (u32*)take((size_t)Nn * D * 4);         // packed K1
    u16*   nV1 = (u16*)take((size_t)Nn * D * 2);         // hi-only V1
    u16*   q1  = (u16*)take((size_t)E * D * 2);          // hi-only bf16
    float* ebuf  = (float*)take((size_t)E * 4);
    float* denom = (float*)take((size_t)2 * Nn * 4);     // layer0 | layer1
    u16* wnh = (u16*)take((size_t)5 * D * D * 2);        // node weights hi (stacked)
    u16* wnl = (u16*)take((size_t)5 * D * D * 2);        // node weights lo
    u16* wff1h = (u16*)take((size_t)D * D * 2); u16* wff1l = (u16*)take((size_t)D * D * 2);
    u16* wch = (u16*)take((size_t)D * D * 2);            // composed Wq1@Wff0 hi
    u16* wcl = (u16*)take((size_t)D * D * 2);            // composed lo
    float* bc = (float*)take((size_t)D * 4);             // composed bias
    u16* w3h = (u16*)take((size_t)3 * D * D * 2);
    u16* w4h = (u16*)take((size_t)9 * D * D * 2);
    u16* w5h = (u16*)take((size_t)3 * D * D * 2);

    // ---- adaptive chunk ----
    // zone pre-phase: xph+xpl (4B/elem) + Q0,K0 packed (8B) + V0 hi (2B)
    const size_t nodeB = (size_t)Nn * D * 14;
    size_t rem = ws_size > off + 8192 ? ws_size - off - 8192 : 0;
    size_t cmA = rem / 4096;
    size_t cmB = rem > nodeB ? (rem - nodeB) / 2048 : 0;
    size_t CMs = (cmA * 2048 >= nodeB) ? cmA : cmB;
    CMs = (CMs / 128) * 128;
    if (CMs > (size_t)E) CMs = E;
    if (CMs > 32768) CMs = 32768;       // one co-residency round for gemm2
    if (CMs < 128) CMs = 128;
    const int CM = (int)CMs;

    // chunk planes: 4 slots of CM*D u16. c1h/c1l = slots 0,1;
    // c4 = slots 0-2 (CM*3D, clobbers c1 after it is dead), c5 = slot 3.
    u16* cpl = (u16*)take((size_t)CM * D * 2 * 4);
    u16* c1h = cpl;
    u16* c1l = cpl + (size_t)CM * D;
    u16* c4  = cpl;                                   // CM*3D u16
    u16* c5  = cpl + (size_t)3 * CM * D;              // CM*D u16
    size_t zoneB = (size_t)CM * 2048 > nodeB ? (size_t)CM * 2048 : nodeB;
    char* zone = (char*)take(zoneB);
    u16* c2n = (u16*)zone;                            // CM*D u16 (pass 2)
    u16* c3  = (u16*)(zone + (size_t)CM * D * 2);     // CM*3D u16 (pass 2)
    u16* xph = (u16*)zone;                            // Nn*D hi plane (pre)
    u16* xpl = xph + (size_t)Nn * D;                  // Nn*D lo plane
    u32* zQ0 = (u32*)(zone + (size_t)Nn * D * 4);     // packed Q0
    u32* zK0 = zQ0 + (size_t)Nn * D;                  // packed K0
    u16* zV0 = (u16*)(zK0 + (size_t)Nn * D);          // hi-only V0

    dim3 blk(256);
    dim3 blk2(512);
    int gridE4  = (E + 3) / 4;
    const int DD = D * D;               // 65536 = 2^16

    // ---- pack x + single up-front denom init (both layers) ----
    pack_x<<<(Nn * D + 255) / 256, 256, 0, stream>>>(x, xph, xpl, Nn * D);
    seg_init<<<(2 * Nn + 255) / 256, 256, 0, stream>>>(denom, 2 * Nn);

    // ---- single-launch weight conversion (21 regions) ----
    WcvA wa;
    const float* ws_[21] = {Wq, Wk, Wv, Wk + DD, Wv + DD, Wff + DD,
                            W3, W3 + DD, W3 + 2 * DD,
                            W4, W4 + DD, W4 + 2 * DD, W4 + 3 * DD, W4 + 4 * DD,
                            W4 + 5 * DD, W4 + 6 * DD, W4 + 7 * DD, W4 + 8 * DD,
                            W5, W5 + DD, W5 + 2 * DD};
    u16* wh_[21] = {wnh, wnh + DD, wnh + 2 * DD, wnh + 3 * DD, wnh + 4 * DD, wff1h,
                    w3h, w3h + DD, w3h + 2 * DD,
                    w4h, w4h + DD, w4h + 2 * DD, w4h + 3 * DD, w4h + 4 * DD,
                    w4h + 5 * DD, w4h + 6 * DD, w4h + 7 * DD, w4h + 8 * DD,
                    w5h, w5h + DD, w5h + 2 * DD};
    u16* wl_[21] = {wnl, wnl + DD, wnl + 2 * DD, wnl + 3 * DD, wnl + 4 * DD, wff1l,
                    nullptr, nullptr, nullptr,
                    nullptr, nullptr, nullptr, nullptr, nullptr,
                    nullptr, nullptr, nullptr, nullptr,
                    nullptr, nullptr, nullptr};
    for (int r = 0; r < 21; ++r) { wa.s[r] = ws_[r]; wa.h[r] = wh_[r]; wa.l[r] = wl_[r]; }
    wconv_all<<<(21 * DD) / 256, 256, 0, stream>>>(wa, 21 * DD);

    // ---- compose pass-1 weights: Wc = Wq1 @ Wff0, bc = bq1 + Wq1 @ bff ----
    wcomb<<<256, 256, 0, stream>>>(Wq + DD, Wff, bff, bq + D, wch, wcl, bc);

    // ---- node projections: all 5 in one batched dispatch ----
    int gN = (Nn + 127) / 128;
    G3N g3;
    g3.bias[0] = bq;     g3.o32[0] = zQ0;     g3.o16[0] = nullptr;
    g3.bias[1] = bk;     g3.o32[1] = zK0;     g3.o16[1] = nullptr;
    g3.bias[2] = bv;     g3.o32[2] = nullptr; g3.o16[2] = zV0;
    g3.bias[3] = bk + D; g3.o32[3] = nK1;     g3.o16[3] = nullptr;
    g3.bias[4] = bv + D; g3.o32[4] = nullptr; g3.o16[4] = nV1;
    gemm3n<<<dim3(gN, 5), blk2, 0, stream>>>(xph, xpl, wnh, wnl, g3, Nn, D);

    // ---- layer-0 segment softmax (exp-direct, no max-sub) ----
    attn_alpha<u32, 0><<<gridE4, blk, 0, stream>>>(src, dst, zQ0, zK0, ebuf, denom, E);

    // ---- pass 1 (chunked): attnLN0 -> (Wq1@Wff0 composed) -> q1 ----
    for (int e0 = 0; e0 < E; e0 += CM) {
        int cm = E - e0 < CM ? E - e0 : CM;
        int gE4 = (cm + 3) / 4;
        dim3 gD3(cm / 128);
        attn_out_ln<u32, 0><<<gE4, blk, 0, stream>>>(src, dst, zQ0, zV0, ebuf, denom,
                                                     ga, ba, c1h, c1l, e0, cm);
        gemm3w<0><<<gD3, blk2, 0, stream>>>(c1h, c1l, wch, wcl, bc,
                                            (const float*)nullptr, (const float*)nullptr,
                                            q1 + (size_t)e0 * D, cm, D);
    }

    // ---- layer-1 segment softmax (state at denom+Nn) ----
    attn_alpha<u16, 1><<<gridE4, blk, 0, stream>>>(src, dst, q1, nK1, ebuf,
                                                   denom + Nn, E);

    // ---- pass 2 (chunked) ----
    for (int e0 = 0; e0 < E; e0 += CM) {
        int cm = E - e0 < CM ? E - e0 : CM;
        int gE4 = (cm + 3) / 4;
        dim3 gD3(cm / 128);
        dim3 g2a(cm / 128, (3 * D) / 256);
        dim3 g2b(cm / 128, D / 256);
        attn_out_ln<u16, 1><<<gE4, blk, 0, stream>>>(src, dst, q1, nV1, ebuf,
                                                     denom + Nn,
                                                     ga + D, ba + D, c1h, c1l, e0, cm);
        // Wff1 GEMM with fused lrelu + LN epilogue -> c2n
        gemm3w<1><<<gD3, blk2, 0, stream>>>(c1h, c1l, wff1h, wff1l, bff + D,
                                            gf, bf, c2n, cm, D);
        gemm2<1><<<g2a, blk2, 0, stream>>>(c2n, w3h, b3, c3, cm, 3 * D, D);
        gemm2<1><<<g2a, blk2, 0, stream>>>(c3, w4h, b4, c4, cm, 3 * D, 3 * D);
        gemm2<0><<<g2b, blk2, 0, stream>>>(c4, w5h, b5, c5, cm, D, 3 * D);
        final_k<<<gE4, blk, 0, stream>>>(c5, c2n, gfin, bfin, Wvec, bvec,
                                         (float*)d_out, e0, cm);
    }
}

// Round 11
// 1121.589 us; speedup vs baseline: 1.1506x; 1.0519x over previous
//
#include <hip/hip_runtime.h>

#define D 256

typedef unsigned short u16;
typedef unsigned int u32;
typedef __attribute__((ext_vector_type(8))) short short8;
typedef __attribute__((ext_vector_type(4))) float f32x4;
typedef __attribute__((ext_vector_type(16))) float f32x16;

// ---------------- bf16 <-> f32, split-pack ----------------
__device__ __forceinline__ float b2f(u16 u) {
    return __uint_as_float(((u32)u) << 16);
}
__device__ __forceinline__ u16 f2b(float f) {
    u32 u = __float_as_uint(f);
    return (u16)((u + 0x7FFFu + ((u >> 16) & 1u)) >> 16);  // RNE
}
__device__ __forceinline__ u32 packf(float v) {
    u16 h = f2b(v);
    u16 l = f2b(v - b2f(h));
    return ((u32)h << 16) | l;
}
__device__ __forceinline__ float unpackf(u32 p) {
    return b2f((u16)(p >> 16)) + b2f((u16)(p & 0xffffu));
}
template<typename T> __device__ __forceinline__ float ld1(const T* p);
template<> __device__ __forceinline__ float ld1<u16>(const u16* p) { return b2f(*p); }
template<> __device__ __forceinline__ float ld1<u32>(const u32* p) { return unpackf(*p); }

__device__ __forceinline__ float wred(float v) {
#pragma unroll
    for (int m = 32; m; m >>= 1) v += __shfl_xor(v, m);
    return v;
}

// async global(16B/lane) -> LDS (wave-uniform base + lane*16)
__device__ __forceinline__ void gl_lds16(const u16* g, u16* l) {
    __builtin_amdgcn_global_load_lds(
        (__attribute__((address_space(1))) void*)(u16*)g,
        (__attribute__((address_space(3))) void*)l, 16, 0, 0);
}

// ======== gemm2: single-term MFMA GEMM, R2-verified config (locked) ========
// C = act(A[M,K] @ W[N,K]^T + b). A bf16 u16; W hi-plane u16.
// 128x256 tile, single 48KB buffer, 2 barriers/step, 3 blocks/CU. BK=64.
// Conflict-free swizzle key(r) = (r&7) ^ ((r>>3)&3) (measured: conflicts=0).
// Used for W3/W4 (N=768: grid 768 blocks = one full co-residency round).
// M%128==0, N%256==0, K%64==0.
template<int ACT>
__global__ __launch_bounds__(512, 4)
void gemm2(const u16* __restrict__ A, const u16* __restrict__ Whi,
           const float* __restrict__ bias, u16* __restrict__ C,
           int M, int N, int K)
{
    __shared__ u16 sA[128 * 64];       // 16 KB
    __shared__ u16 sWh[256 * 64];      // 32 KB

    const int tid  = threadIdx.x;
    const int lane = tid & 63;
    const int w    = tid >> 6;             // wave 0..7
    const int wm   = (w & 1) * 64;
    const int wn   = (w >> 1) * 64;
    const int row0 = blockIdx.x * 128;
    const int col0 = blockIdx.y * 256;

    f32x16 acc[2][2];
#pragma unroll
    for (int i = 0; i < 2; ++i)
#pragma unroll
        for (int j = 0; j < 2; ++j)
#pragma unroll
            for (int r = 0; r < 16; ++r) acc[i][j][r] = 0.f;

    const int r31   = lane & 31;
    const int khalf = lane >> 5;
    const int skey  = (r31 & 7) ^ ((r31 >> 3) & 3);
    const int l8r = lane >> 3;
    const int l8c = lane & 7;

    for (int k0 = 0; k0 < K; k0 += 64) {
#pragma unroll
        for (int s = 0; s < 4; ++s) {
            const int rbase = w * 32 + s * 8;
            const int row = rbase + l8r;
            const int gch = l8c ^ (row & 7) ^ s;
            const size_t gW = (size_t)(col0 + row) * K + k0 + gch * 8;
            gl_lds16(Whi + gW, sWh + rbase * 64);
        }
#pragma unroll
        for (int s = 0; s < 2; ++s) {
            const int rbase = w * 16 + s * 8;
            const int row = rbase + l8r;
            const int gch = l8c ^ (row & 7) ^ ((w * 2 + s) & 3);
            const size_t gA = (size_t)(row0 + row) * K + k0 + gch * 8;
            gl_lds16(A + gA, sA + rbase * 64);
        }
        __syncthreads();

#pragma unroll
        for (int w4 = 0; w4 < 4; ++w4) {
            const int slot = ((w4 * 2 + khalf) ^ skey) * 8;
            short8 af[2], wf[2];
#pragma unroll
            for (int i = 0; i < 2; ++i)
                af[i] = *(const short8*)(sA + (wm + i * 32 + r31) * 64 + slot);
#pragma unroll
            for (int j = 0; j < 2; ++j)
                wf[j] = *(const short8*)(sWh + (wn + j * 32 + r31) * 64 + slot);
#pragma unroll
            for (int i = 0; i < 2; ++i)
#pragma unroll
                for (int j = 0; j < 2; ++j)
                    acc[i][j] = __builtin_amdgcn_mfma_f32_32x32x16_bf16(af[i], wf[j], acc[i][j], 0, 0, 0);
        }
        __syncthreads();
    }

#pragma unroll
    for (int j = 0; j < 2; ++j) {
        const int col = col0 + wn + j * 32 + r31;
        const float bb = bias[col];
#pragma unroll
        for (int i = 0; i < 2; ++i) {
            const int rowb = row0 + wm + i * 32 + 4 * khalf;
#pragma unroll
            for (int reg = 0; reg < 16; ++reg) {
                const int row = rowb + (reg & 3) + 8 * (reg >> 2);
                float v = acc[i][j][reg] + bb;
                if (ACT) v = v > 0.f ? v : 0.2f * v;
                C[(size_t)row * N + col] = f2b(v);
            }
        }
    }
}

// ======== gemm2h: 64-row single-term GEMM for W5 (N=256) ========
// R10 analysis: W5's grid at 128-row tiles is cm/128 = 256 blocks vs a
// 768-block co-residency capacity -> 2/3 of the GPU idle. 64-row tile:
// LDS 8+32 = 40 KB -> 4 blocks/CU (1024 capacity), grid cm/64 = 512.
// Wave tile 32x64 (acc 2 x f32x16). Same verified swizzle (key invariant
// under +32 row offsets). M%64==0, N%256==0, K%64==0.
__global__ __launch_bounds__(512, 4)
void gemm2h(const u16* __restrict__ A, const u16* __restrict__ Whi,
            const float* __restrict__ bias, u16* __restrict__ C,
            int M, int N, int K)
{
    __shared__ u16 sA[64 * 64];        // 8 KB
    __shared__ u16 sWh[256 * 64];      // 32 KB

    const int tid  = threadIdx.x;
    const int lane = tid & 63;
    const int w    = tid >> 6;             // wave 0..7
    const int wm   = (w & 1) * 32;
    const int wn   = (w >> 1) * 64;
    const int row0 = blockIdx.x * 64;
    const int col0 = blockIdx.y * 256;

    f32x16 acc[2];
#pragma unroll
    for (int j = 0; j < 2; ++j)
#pragma unroll
        for (int r = 0; r < 16; ++r) acc[j][r] = 0.f;

    const int r31   = lane & 31;
    const int khalf = lane >> 5;
    const int skey  = (r31 & 7) ^ ((r31 >> 3) & 3);
    const int l8r = lane >> 3;
    const int l8c = lane & 7;

    for (int k0 = 0; k0 < K; k0 += 64) {
#pragma unroll
        for (int s = 0; s < 4; ++s) {          // W: 256 rows, 4 segs/wave
            const int rbase = w * 32 + s * 8;
            const int row = rbase + l8r;
            const int gch = l8c ^ (row & 7) ^ s;
            const size_t gW = (size_t)(col0 + row) * K + k0 + gch * 8;
            gl_lds16(Whi + gW, sWh + rbase * 64);
        }
        {                                      // A: 64 rows, 1 seg/wave
            const int rbase = w * 8;
            const int row = rbase + l8r;       // row>>3 == w
            const int gch = l8c ^ l8r ^ (w & 3);
            const size_t gA = (size_t)(row0 + row) * K + k0 + gch * 8;
            gl_lds16(A + gA, sA + rbase * 64);
        }
        __syncthreads();

#pragma unroll
        for (int w4 = 0; w4 < 4; ++w4) {
            const int slot = ((w4 * 2 + khalf) ^ skey) * 8;
            short8 af, wf[2];
            af = *(const short8*)(sA + (wm + r31) * 64 + slot);
#pragma unroll
            for (int j = 0; j < 2; ++j)
                wf[j] = *(const short8*)(sWh + (wn + j * 32 + r31) * 64 + slot);
#pragma unroll
            for (int j = 0; j < 2; ++j)
                acc[j] = __builtin_amdgcn_mfma_f32_32x32x16_bf16(af, wf[j], acc[j], 0, 0, 0);
        }
        __syncthreads();
    }

#pragma unroll
    for (int j = 0; j < 2; ++j) {
        const int col = col0 + wn + j * 32 + r31;
        const float bb = bias[col];
        const int rowb = row0 + wm + 4 * khalf;
#pragma unroll
        for (int reg = 0; reg < 16; ++reg) {
            const int row = rowb + (reg & 3) + 8 * (reg >> 2);
            C[(size_t)row * N + col] = f2b(acc[j][reg] + bb);
        }
    }
}

// ======== gemm3w: 3-term split MFMA GEMM, 64-row tile, N=256 sweep ========
// C = A @ W^T + b with A = Ah + Al, W = Wh + Wl (3-term: hh + hl + lh).
// R10: 64-row tile (was 128) -> LDS 4+4+16+16 = 40 KB -> 4 blocks/CU,
// grid cm/64 = 512 blocks (was 256 vs 768 capacity = 2/3 GPU idle).
// A staging: waves 0-3 stage Ahi seg (w&3)*16, waves 4-7 stage Alo.
// 16x16x32, BK=32. Block owns COMPLETE rows.
// LNF=0: hi-only bf16 epilogue. LNF=1: fused lrelu + row-LN epilogue.
// M%64==0, K%32==0.
template<int LNF>
__global__ __launch_bounds__(512, 4)
void gemm3w(const u16* __restrict__ Ah, const u16* __restrict__ Al,
            const u16* __restrict__ Wh_, const u16* __restrict__ Wl_,
            const float* __restrict__ bias,
            const float* __restrict__ lng, const float* __restrict__ lnb,
            u16* __restrict__ Ch, int M, int K)
{
    constexpr int N = 256;
    __shared__ u16 sAhi[64 * 32];      // 4 KB
    __shared__ u16 sAlo[64 * 32];      // 4 KB
    __shared__ u16 sWhi[256 * 32];     // 16 KB
    __shared__ u16 sWlo[256 * 32];     // 16 KB

    const int tid  = threadIdx.x;
    const int lane = tid & 63;
    const int w    = tid >> 6;
    const int wm   = (w & 1) * 32;
    const int wn   = (w >> 1) * 64;
    const int row0 = blockIdx.x * 64;

    f32x4 acc[2][4];
#pragma unroll
    for (int i = 0; i < 2; ++i)
#pragma unroll
        for (int j = 0; j < 4; ++j) acc[i][j] = (f32x4){0.f, 0.f, 0.f, 0.f};

    const int lrow = lane >> 2;
    const int gck  = (lane & 3) ^ ((lane >> 3) & 3);
    const int r15 = lane & 15;
    const int hi16 = lane >> 4;
    const int rck = (hi16 ^ ((r15 >> 1) & 3)) * 8;

    for (int k0 = 0; k0 < K; k0 += 32) {
#pragma unroll
        for (int s = 0; s < 2; ++s) {                  // W: 256 rows
            const int rbase = w * 32 + s * 16;
            const size_t gW = (size_t)(rbase + lrow) * K + k0 + gck * 8;
            gl_lds16(Wh_ + gW, sWhi + rbase * 32);
            gl_lds16(Wl_ + gW, sWlo + rbase * 32);
        }
        {                                              // A: 64 rows, hi|lo split
            const int rbase = (w & 3) * 16;            // wave-uniform
            const size_t gA = (size_t)(row0 + rbase + lrow) * K + k0 + gck * 8;
            if (w < 4) gl_lds16(Ah + gA, sAhi + rbase * 32);
            else       gl_lds16(Al + gA, sAlo + rbase * 32);
        }
        __syncthreads();

        short8 ah[2], al[2], wh[4], wl[4];
#pragma unroll
        for (int i = 0; i < 2; ++i) {
            const int offA = (wm + i * 16 + r15) * 32 + rck;
            ah[i] = *(const short8*)(sAhi + offA);
            al[i] = *(const short8*)(sAlo + offA);
        }
#pragma unroll
        for (int j = 0; j < 4; ++j) {
            const int offW = (wn + j * 16 + r15) * 32 + rck;
            wh[j] = *(const short8*)(sWhi + offW);
            wl[j] = *(const short8*)(sWlo + offW);
        }
#pragma unroll
        for (int i = 0; i < 2; ++i)
#pragma unroll
            for (int j = 0; j < 4; ++j) {
                acc[i][j] = __builtin_amdgcn_mfma_f32_16x16x32_bf16(ah[i], wh[j], acc[i][j], 0, 0, 0);
                acc[i][j] = __builtin_amdgcn_mfma_f32_16x16x32_bf16(ah[i], wl[j], acc[i][j], 0, 0, 0);
                acc[i][j] = __builtin_amdgcn_mfma_f32_16x16x32_bf16(al[i], wh[j], acc[i][j], 0, 0, 0);
            }
        __syncthreads();
    }

    if (LNF == 0) {
#pragma unroll
        for (int j = 0; j < 4; ++j) {
            const int col = wn + j * 16 + r15;
            const float bb = bias[col];
#pragma unroll
            for (int i = 0; i < 2; ++i) {
                const int rowb = row0 + wm + i * 16 + hi16 * 4;
#pragma unroll
                for (int r = 0; r < 4; ++r)
                    Ch[(size_t)(rowb + r) * N + col] = f2b(acc[i][j][r] + bb);
            }
        }
    } else {
        // fused lrelu + row-LN. red: s1 at [lr*4+cg], s2 at [(64+lr)*4+cg].
        float* red = (float*)sWhi;                 // 2 KB of the 16 KB buffer
        const int cg = w >> 1;
#pragma unroll
        for (int i = 0; i < 2; ++i) {
            float s1[4] = {0.f, 0.f, 0.f, 0.f};
            float s2[4] = {0.f, 0.f, 0.f, 0.f};
#pragma unroll
            for (int j = 0; j < 4; ++j) {
                const float bb = bias[wn + j * 16 + r15];
#pragma unroll
                for (int r = 0; r < 4; ++r) {
                    float v = acc[i][j][r] + bb;
                    float a = v > 0.f ? v : 0.2f * v;
                    s1[r] += a; s2[r] += a * a;
                }
            }
#pragma unroll
            for (int r = 0; r < 4; ++r) {
#pragma unroll
                for (int m = 8; m; m >>= 1) {
                    s1[r] += __shfl_xor(s1[r], m);
                    s2[r] += __shfl_xor(s2[r], m);
                }
            }
            if (r15 == 0) {
#pragma unroll
                for (int r = 0; r < 4; ++r) {
                    const int lr = wm + i * 16 + hi16 * 4 + r;
                    red[lr * 4 + cg] = s1[r];
                    red[(64 + lr) * 4 + cg] = s2[r];
                }
            }
        }
        __syncthreads();
#pragma unroll
        for (int i = 0; i < 2; ++i) {
#pragma unroll
            for (int r = 0; r < 4; ++r) {
                const int lr = wm + i * 16 + hi16 * 4 + r;
                float m = (red[lr * 4 + 0] + red[lr * 4 + 1] +
                           red[lr * 4 + 2] + red[lr * 4 + 3]) * (1.f / 256.f);
                float e2 = (red[(64 + lr) * 4 + 0] + red[(64 + lr) * 4 + 1] +
                            red[(64 + lr) * 4 + 2] + red[(64 + lr) * 4 + 3]) * (1.f / 256.f);
                float rstd = rsqrtf(e2 - m * m + 1e-5f);
                const size_t grow = (size_t)(row0 + lr);
#pragma unroll
                for (int j = 0; j < 4; ++j) {
                    const int col = wn + j * 16 + r15;
                    float v = acc[i][j][r] + bias[col];
                    float a = v > 0.f ? v : 0.2f * v;
                    Ch[grow * N + col] = f2b((a - m) * rstd * lng[col] + lnb[col]);
                }
            }
        }
    }
}

// ======== gemm3n: node-projection batched GEMM, 5-way (single dispatch) =====
// y = blockIdx.y in 0..4: W = Whi/Wlo + y*N*K. Per-y output: packed u32
// (o32) OR hi-only bf16 (o16). V outputs (y=2,4) are hi-only.
struct G3N { const float* bias[5]; u32* o32[5]; u16* o16[5]; };
__global__ __launch_bounds__(512, 4)
void gemm3n(const u16* __restrict__ Ah, const u16* __restrict__ Al,
            const u16* __restrict__ Whi, const u16* __restrict__ Wlo,
            G3N a, int M, int K)
{
    constexpr int N = 256;
    __shared__ u16 sAhi[128 * 32];
    __shared__ u16 sAlo[128 * 32];
    __shared__ u16 sWhi[256 * 32];
    __shared__ u16 sWlo[256 * 32];

    const int tid  = threadIdx.x;
    const int lane = tid & 63;
    const int w    = tid >> 6;
    const int wm   = (w & 1) * 64;
    const int wn   = (w >> 1) * 64;
    const int row0 = blockIdx.x * 128;
    const int y    = blockIdx.y;
    const float* bias = a.bias[y];
    const u16* Wh = Whi + (size_t)y * N * K;
    const u16* Wl = Wlo + (size_t)y * N * K;
    u32* C32 = a.o32[y];
    u16* C16 = a.o16[y];

    f32x4 acc[4][4];
#pragma unroll
    for (int i = 0; i < 4; ++i)
#pragma unroll
        for (int j = 0; j < 4; ++j) acc[i][j] = (f32x4){0.f, 0.f, 0.f, 0.f};

    const int lrow = lane >> 2;
    const int gck  = (lane & 3) ^ ((lane >> 3) & 3);
    const int r15 = lane & 15;
    const int rck = ((lane >> 4) ^ ((r15 >> 1) & 3)) * 8;

    for (int k0 = 0; k0 < K; k0 += 32) {
#pragma unroll
        for (int s = 0; s < 2; ++s) {
            const int rbase = w * 32 + s * 16;
            const size_t gW = (size_t)(rbase + lrow) * K + k0 + gck * 8;
            gl_lds16(Wh + gW, sWhi + rbase * 32);
            gl_lds16(Wl + gW, sWlo + rbase * 32);
        }
        {
            const int rbase = w * 16;
            int arow = row0 + rbase + lrow;
            if (arow >= M) arow = M - 1;               // per-lane source clamp
            const size_t gA = (size_t)arow * K + k0 + gck * 8;
            gl_lds16(Ah + gA, sAhi + rbase * 32);
            gl_lds16(Al + gA, sAlo + rbase * 32);
        }
        __syncthreads();

        short8 ah[4], al[4], wh[4], wl[4];
#pragma unroll
        for (int i = 0; i < 4; ++i) {
            const int offA = (wm + i * 16 + r15) * 32 + rck;
            ah[i] = *(const short8*)(sAhi + offA);
            al[i] = *(const short8*)(sAlo + offA);
        }
#pragma unroll
        for (int j = 0; j < 4; ++j) {
            const int offW = (wn + j * 16 + r15) * 32 + rck;
            wh[j] = *(const short8*)(sWhi + offW);
            wl[j] = *(const short8*)(sWlo + offW);
        }
#pragma unroll
        for (int i = 0; i < 4; ++i)
#pragma unroll
            for (int j = 0; j < 4; ++j) {
                acc[i][j] = __builtin_amdgcn_mfma_f32_16x16x32_bf16(ah[i], wh[j], acc[i][j], 0, 0, 0);
                acc[i][j] = __builtin_amdgcn_mfma_f32_16x16x32_bf16(ah[i], wl[j], acc[i][j], 0, 0, 0);
                acc[i][j] = __builtin_amdgcn_mfma_f32_16x16x32_bf16(al[i], wh[j], acc[i][j], 0, 0, 0);
            }
        __syncthreads();
    }

#pragma unroll
    for (int j = 0; j < 4; ++j) {
        const int col = wn + j * 16 + r15;
        const float bb = bias[col];
#pragma unroll
        for (int i = 0; i < 4; ++i) {
            const int rowb = row0 + wm + i * 16 + (lane >> 4) * 4;
#pragma unroll
            for (int r = 0; r < 4; ++r) {
                const int row = rowb + r;
                if (row < M) {
                    float v = acc[i][j][r] + bb;
                    if (C16) C16[(size_t)row * N + col] = f2b(v);
                    else     C32[(size_t)row * N + col] = packf(v);
                }
            }
        }
    }
}

// ---------------- x fp32 -> hi/lo bf16 planes ----------------
__global__ void pack_x(const float* __restrict__ x, u16* __restrict__ xh,
                       u16* __restrict__ xl, int n)
{
    int i = blockIdx.x * 256 + threadIdx.x;
    if (i < n) {
        float v = x[i];
        u16 h = f2b(v);
        xh[i] = h;
        xl[i] = f2b(v - b2f(h));
    }
}

// ---------------- weight conversions in ONE launch (21 regions of DD) -------
struct WcvA { const float* s[21]; u16* h[21]; u16* l[21]; };
__global__ __launch_bounds__(256)
void wconv_all(WcvA a, int n)
{
    int i = blockIdx.x * 256 + threadIdx.x;
    if (i >= n) return;
    int r = i >> 16;
    int o = i & 65535;
    float v = a.s[r][o];
    u16 hh = f2b(v);
    a.h[r][o] = hh;
    if (a.l[r]) a.l[r][o] = f2b(v - b2f(hh));
}

// ---------------- Wc = Wq1 @ Wff0 (fp32), bc = bq1 + Wq1 @ bff --------------
__global__ __launch_bounds__(256)
void wcomb(const float* __restrict__ Wq1, const float* __restrict__ Wff0,
           const float* __restrict__ bff, const float* __restrict__ bq1,
           u16* __restrict__ wch, u16* __restrict__ wcl, float* __restrict__ bc)
{
    const int o = blockIdx.x;
    const int j = threadIdx.x;
    const float* wq = Wq1 + (size_t)o * 256;
    float s = 0.f;
    for (int k = 0; k < 256; ++k)
        s = fmaf(wq[k], Wff0[(size_t)k * 256 + j], s);
    u16 h = f2b(s);
    wch[(size_t)o * 256 + j] = h;
    wcl[(size_t)o * 256 + j] = f2b(s - b2f(h));
    float p = wq[j] * bff[j];
    p = wred(p);
    __shared__ float ps[4];
    if ((j & 63) == 0) ps[j >> 6] = p;
    __syncthreads();
    if (j == 0) bc[o] = bq1[o] + ps[0] + ps[1] + ps[2] + ps[3];
}

// ---------------- segment-softmax state init (denom only) ----------------
__global__ void seg_init(float* __restrict__ denom, int n)
{
    int i = blockIdx.x * 256 + threadIdx.x;
    if (i < n) denom[i] = 0.f;
}

// ---------------- exp-direct segment softmax: ebuf = exp(q.k), denom += -----
// No max-subtraction: alpha ~ N(0, ~10); exp stays far inside f32 range.
template<typename TQ, int MODE>
__global__ __launch_bounds__(256)
void attn_alpha(const int* __restrict__ src, const int* __restrict__ dst,
                const TQ* __restrict__ qn, const u32* __restrict__ kn,
                float* __restrict__ ebuf, float* __restrict__ denom, int E)
{
    int e = blockIdx.x * 4 + (threadIdx.x >> 6);
    int lane = threadIdx.x & 63;
    if (e >= E) return;
    int s = src[e], d = dst[e];
    const TQ* qp = MODE ? (qn + (size_t)e * D) : (qn + (size_t)d * D);
    const u32* kp = kn + (size_t)s * D;
    float dot = 0.f;
#pragma unroll
    for (int j = 0; j < 4; ++j)
        dot += ld1(qp + lane * 4 + j) * unpackf(kp[lane * 4 + j]);
    dot = wred(dot);
    if (lane == 0) {
        float ex = expf(dot);
        ebuf[e] = ex;
        atomicAdd(denom + d, ex);
    }
}

// ---------------- out(local, hi/lo planes) = LN(q + attn*v[src]) ----------------
// v is hi-only bf16.
template<typename TQ, int MODE>
__global__ __launch_bounds__(256)
void attn_out_ln(const int* __restrict__ src, const int* __restrict__ dst,
                 const TQ* __restrict__ qn, const u16* __restrict__ vn,
                 const float* __restrict__ ebuf, const float* __restrict__ denom,
                 const float* __restrict__ g, const float* __restrict__ bb,
                 u16* __restrict__ oh, u16* __restrict__ ol, int e0, int cm)
{
    int le = blockIdx.x * 4 + (threadIdx.x >> 6);
    int lane = threadIdx.x & 63;
    if (le >= cm) return;
    int ge = e0 + le;
    int s = src[ge], d = dst[ge];
    float attn = ebuf[ge] / denom[d];
    const TQ* qp = MODE ? (qn + (size_t)ge * D) : (qn + (size_t)d * D);
    const u16* vp = vn + (size_t)s * D;
    int d0 = lane * 4;
    ushort4 vv = *(const ushort4*)(vp + d0);
    float a0 = ld1(qp + d0 + 0) + attn * b2f(vv.x);
    float a1 = ld1(qp + d0 + 1) + attn * b2f(vv.y);
    float a2 = ld1(qp + d0 + 2) + attn * b2f(vv.z);
    float a3 = ld1(qp + d0 + 3) + attn * b2f(vv.w);
    float mean = wred(a0 + a1 + a2 + a3) * (1.f / D);
    float c0 = a0 - mean, c1 = a1 - mean, c2 = a2 - mean, c3 = a3 - mean;
    float var = wred(c0 * c0 + c1 * c1 + c2 * c2 + c3 * c3) * (1.f / D);
    float rstd = rsqrtf(var + 1e-5f);
    float t0 = c0 * rstd * g[d0 + 0] + bb[d0 + 0];
    float t1 = c1 * rstd * g[d0 + 1] + bb[d0 + 1];
    float t2 = c2 * rstd * g[d0 + 2] + bb[d0 + 2];
    float t3 = c3 * rstd * g[d0 + 3] + bb[d0 + 3];
    size_t base = (size_t)le * D + d0;
    ushort4 ph, pl;
    ph.x = f2b(t0); pl.x = f2b(t0 - b2f(ph.x));
    ph.y = f2b(t1); pl.y = f2b(t1 - b2f(ph.y));
    ph.z = f2b(t2); pl.z = f2b(t2 - b2f(ph.z));
    ph.w = f2b(t3); pl.w = f2b(t3 - b2f(ph.w));
    *(ushort4*)(oh + base) = ph;
    *(ushort4*)(ol + base) = pl;
}

// ---------------- out[e0+le] = dot(LN(h+q), Wvec) + bvec (u16 h, u16 q) ----------------
__global__ __launch_bounds__(256)
void final_k(const u16* __restrict__ hp, const u16* __restrict__ qp,
             const float* __restrict__ gfin, const float* __restrict__ bfin,
             const float* __restrict__ wvec, const float* __restrict__ bvec,
             float* __restrict__ out, int e0, int cm)
{
    int le = blockIdx.x * 4 + (threadIdx.x >> 6);
    int lane = threadIdx.x & 63;
    if (le >= cm) return;
    size_t base = (size_t)le * D + lane * 4;
    ushort4 hv = *(const ushort4*)(hp + base);
    ushort4 qv = *(const ushort4*)(qp + base);
    float a0 = b2f(hv.x) + b2f(qv.x);
    float a1 = b2f(hv.y) + b2f(qv.y);
    float a2 = b2f(hv.z) + b2f(qv.z);
    float a3 = b2f(hv.w) + b2f(qv.w);
    float mean = wred(a0 + a1 + a2 + a3) * (1.f / D);
    float c0 = a0 - mean, c1 = a1 - mean, c2 = a2 - mean, c3 = a3 - mean;
    float var = wred(c0 * c0 + c1 * c1 + c2 * c2 + c3 * c3) * (1.f / D);
    float rstd = rsqrtf(var + 1e-5f);
    int d0 = lane * 4;
    float t0 = c0 * rstd * gfin[d0 + 0] + bfin[d0 + 0];
    float t1 = c1 * rstd * gfin[d0 + 1] + bfin[d0 + 1];
    float t2 = c2 * rstd * gfin[d0 + 2] + bfin[d0 + 2];
    float t3 = c3 * rstd * gfin[d0 + 3] + bfin[d0 + 3];
    float part = t0 * wvec[d0 + 0] + t1 * wvec[d0 + 1] +
                 t2 * wvec[d0 + 2] + t3 * wvec[d0 + 3];
    part = wred(part);
    if (lane == 0) out[e0 + le] = part + bvec[0];
}

extern "C" void kernel_launch(void* const* d_in, const int* in_sizes, int n_in,
                              void* d_out, int out_size, void* d_ws, size_t ws_size,
                              hipStream_t stream)
{
    const int*   ei   = (const int*)d_in[0];
    const float* x    = (const float*)d_in[1];
    const float* Wq   = (const float*)d_in[2];
    const float* bq   = (const float*)d_in[3];
    const float* Wk   = (const float*)d_in[4];
    const float* bk   = (const float*)d_in[5];
    const float* Wv   = (const float*)d_in[6];
    const float* bv   = (const float*)d_in[7];
    const float* Wff  = (const float*)d_in[8];
    const float* bff  = (const float*)d_in[9];
    const float* ga   = (const float*)d_in[10];
    const float* ba   = (const float*)d_in[11];
    const float* gf   = (const float*)d_in[12];
    const float* bf   = (const float*)d_in[13];
    const float* gfin = (const float*)d_in[14];
    const float* bfin = (const float*)d_in[15];
    const float* W3   = (const float*)d_in[16];
    const float* b3   = (const float*)d_in[17];
    const float* W4   = (const float*)d_in[18];
    const float* b4   = (const float*)d_in[19];
    const float* W5   = (const float*)d_in[20];
    const float* b5   = (const float*)d_in[21];
    const float* Wvec = (const float*)d_in[22];
    const float* bvec = (const float*)d_in[23];

    const int E  = in_sizes[0] / 2;     // 160000
    const int Nn = in_sizes[1] / D;
    const int* src = ei;
    const int* dst = ei + E;

    // ---- workspace carve: fixed region ----
    char* base = (char*)d_ws;
    size_t off = 0;
    auto take = [&](size_t bytes) -> void* {
        off = (off + 255) & ~(size_t)255;
        void* r = base + off;
        off += bytes;
        return r;
    };
    u32*   nK1 = (u32*)take((size_t)Nn * D * 4);         // packed K1
    u16*   nV1 = (u16*)take((size_t)Nn * D * 2);         // hi-only V1
    u16*   q1  = (u16*)take((size_t)E * D * 2);          // hi-only bf16
    float* ebuf  = (float*)take((size_t)E * 4);
    float* denom = (float*)take((size_t)2 * Nn * 4);     // layer0 | layer1
    u16* wnh = (u16*)take((size_t)5 * D * D * 2);        // node weights hi (stacked)
    u16* wnl = (u16*)take((size_t)5 * D * D * 2);        // node weights lo
    u16* wff1h = (u16*)take((size_t)D * D * 2); u16* wff1l = (u16*)take((size_t)D * D * 2);
    u16* wch = (u16*)take((size_t)D * D * 2);            // composed Wq1@Wff0 hi
    u16* wcl = (u16*)take((size_t)D * D * 2);            // composed lo
    float* bc = (float*)take((size_t)D * 4);             // composed bias
    u16* w3h = (u16*)take((size_t)3 * D * D * 2);
    u16* w4h = (u16*)take((size_t)9 * D * D * 2);
    u16* w5h = (u16*)take((size_t)3 * D * D * 2);

    // ---- adaptive chunk ----
    // zone pre-phase: xph+xpl (4B/elem) + Q0,K0 packed (8B) + V0 hi (2B)
    const size_t nodeB = (size_t)Nn * D * 14;
    size_t rem = ws_size > off + 8192 ? ws_size - off - 8192 : 0;
    size_t cmA = rem / 4096;
    size_t cmB = rem > nodeB ? (rem - nodeB) / 2048 : 0;
    size_t CMs = (cmA * 2048 >= nodeB) ? cmA : cmB;
    CMs = (CMs / 128) * 128;
    if (CMs > (size_t)E) CMs = E;
    if (CMs > 32768) CMs = 32768;       // one co-residency round for gemm2
    if (CMs < 128) CMs = 128;
    const int CM = (int)CMs;

    // chunk planes: 4 slots of CM*D u16. c1h/c1l = slots 0,1;
    // c4 = slots 0-2 (CM*3D, clobbers c1 after it is dead), c5 = slot 3.
    u16* cpl = (u16*)take((size_t)CM * D * 2 * 4);
    u16* c1h = cpl;
    u16* c1l = cpl + (size_t)CM * D;
    u16* c4  = cpl;                                   // CM*3D u16
    u16* c5  = cpl + (size_t)3 * CM * D;              // CM*D u16
    size_t zoneB = (size_t)CM * 2048 > nodeB ? (size_t)CM * 2048 : nodeB;
    char* zone = (char*)take(zoneB);
    u16* c2n = (u16*)zone;                            // CM*D u16 (pass 2)
    u16* c3  = (u16*)(zone + (size_t)CM * D * 2);     // CM*3D u16 (pass 2)
    u16* xph = (u16*)zone;                            // Nn*D hi plane (pre)
    u16* xpl = xph + (size_t)Nn * D;                  // Nn*D lo plane
    u32* zQ0 = (u32*)(zone + (size_t)Nn * D * 4);     // packed Q0
    u32* zK0 = zQ0 + (size_t)Nn * D;                  // packed K0
    u16* zV0 = (u16*)(zK0 + (size_t)Nn * D);          // hi-only V0

    dim3 blk(256);
    dim3 blk2(512);
    int gridE4  = (E + 3) / 4;
    const int DD = D * D;               // 65536 = 2^16

    // ---- pack x + single up-front denom init (both layers) ----
    pack_x<<<(Nn * D + 255) / 256, 256, 0, stream>>>(x, xph, xpl, Nn * D);
    seg_init<<<(2 * Nn + 255) / 256, 256, 0, stream>>>(denom, 2 * Nn);

    // ---- single-launch weight conversion (21 regions) ----
    WcvA wa;
    const float* ws_[21] = {Wq, Wk, Wv, Wk + DD, Wv + DD, Wff + DD,
                            W3, W3 + DD, W3 + 2 * DD,
                            W4, W4 + DD, W4 + 2 * DD, W4 + 3 * DD, W4 + 4 * DD,
                            W4 + 5 * DD, W4 + 6 * DD, W4 + 7 * DD, W4 + 8 * DD,
                            W5, W5 + DD, W5 + 2 * DD};
    u16* wh_[21] = {wnh, wnh + DD, wnh + 2 * DD, wnh + 3 * DD, wnh + 4 * DD, wff1h,
                    w3h, w3h + DD, w3h + 2 * DD,
                    w4h, w4h + DD, w4h + 2 * DD, w4h + 3 * DD, w4h + 4 * DD,
                    w4h + 5 * DD, w4h + 6 * DD, w4h + 7 * DD, w4h + 8 * DD,
                    w5h, w5h + DD, w5h + 2 * DD};
    u16* wl_[21] = {wnl, wnl + DD, wnl + 2 * DD, wnl + 3 * DD, wnl + 4 * DD, wff1l,
                    nullptr, nullptr, nullptr,
                    nullptr, nullptr, nullptr, nullptr, nullptr,
                    nullptr, nullptr, nullptr, nullptr,
                    nullptr, nullptr, nullptr};
    for (int r = 0; r < 21; ++r) { wa.s[r] = ws_[r]; wa.h[r] = wh_[r]; wa.l[r] = wl_[r]; }
    wconv_all<<<(21 * DD) / 256, 256, 0, stream>>>(wa, 21 * DD);

    // ---- compose pass-1 weights: Wc = Wq1 @ Wff0, bc = bq1 + Wq1 @ bff ----
    wcomb<<<256, 256, 0, stream>>>(Wq + DD, Wff, bff, bq + D, wch, wcl, bc);

    // ---- node projections: all 5 in one batched dispatch ----
    int gN = (Nn + 127) / 128;
    G3N g3;
    g3.bias[0] = bq;     g3.o32[0] = zQ0;     g3.o16[0] = nullptr;
    g3.bias[1] = bk;     g3.o32[1] = zK0;     g3.o16[1] = nullptr;
    g3.bias[2] = bv;     g3.o32[2] = nullptr; g3.o16[2] = zV0;
    g3.bias[3] = bk + D; g3.o32[3] = nK1;     g3.o16[3] = nullptr;
    g3.bias[4] = bv + D; g3.o32[4] = nullptr; g3.o16[4] = nV1;
    gemm3n<<<dim3(gN, 5), blk2, 0, stream>>>(xph, xpl, wnh, wnl, g3, Nn, D);

    // ---- layer-0 segment softmax (exp-direct, no max-sub) ----
    attn_alpha<u32, 0><<<gridE4, blk, 0, stream>>>(src, dst, zQ0, zK0, ebuf, denom, E);

    // ---- pass 1 (chunked): attnLN0 -> (Wq1@Wff0 composed) -> q1 ----
    for (int e0 = 0; e0 < E; e0 += CM) {
        int cm = E - e0 < CM ? E - e0 : CM;
        int gE4 = (cm + 3) / 4;
        dim3 gD3(cm / 64);
        attn_out_ln<u32, 0><<<gE4, blk, 0, stream>>>(src, dst, zQ0, zV0, ebuf, denom,
                                                     ga, ba, c1h, c1l, e0, cm);
        gemm3w<0><<<gD3, blk2, 0, stream>>>(c1h, c1l, wch, wcl, bc,
                                            (const float*)nullptr, (const float*)nullptr,
                                            q1 + (size_t)e0 * D, cm, D);
    }

    // ---- layer-1 segment softmax (state at denom+Nn) ----
    attn_alpha<u16, 1><<<gridE4, blk, 0, stream>>>(src, dst, q1, nK1, ebuf,
                                                   denom + Nn, E);

    // ---- pass 2 (chunked) ----
    for (int e0 = 0; e0 < E; e0 += CM) {
        int cm = E - e0 < CM ? E - e0 : CM;
        int gE4 = (cm + 3) / 4;
        dim3 gD3(cm / 64);
        dim3 g2a(cm / 128, (3 * D) / 256);
        attn_out_ln<u16, 1><<<gE4, blk, 0, stream>>>(src, dst, q1, nV1, ebuf,
                                                     denom + Nn,
                                                     ga + D, ba + D, c1h, c1l, e0, cm);
        // Wff1 GEMM with fused lrelu + LN epilogue -> c2n
        gemm3w<1><<<gD3, blk2, 0, stream>>>(c1h, c1l, wff1h, wff1l, bff + D,
                                            gf, bf, c2n, cm, D);
        gemm2<1><<<g2a, blk2, 0, stream>>>(c2n, w3h, b3, c3, cm, 3 * D, D);
        gemm2<1><<<g2a, blk2, 0, stream>>>(c3, w4h, b4, c4, cm, 3 * D, 3 * D);
        // W5: 64-row tile, 512 blocks (was 256 vs 768 capacity)
        gemm2h<<<dim3(cm / 64), blk2, 0, stream>>>(c4, w5h, b5, c5, cm, D, 3 * D);
        final_k<<<gE4, blk, 0, stream>>>(c5, c2n, gfin, bfin, Wvec, bvec,
                                         (float*)d_out, e0, cm);
    }
}